// Round 7
// baseline (316.080 us; speedup 1.0000x reference)
//
#include <hip/hip_runtime.h>
#include <hip/hip_bf16.h>

typedef unsigned short u16;
typedef __attribute__((ext_vector_type(4))) float f32x4;
typedef __attribute__((ext_vector_type(8))) short short8;

#define BN_EPS 1e-5f

__device__ __forceinline__ u16 f2b(float x) {
  union { float f; unsigned int u; } v; v.f = x;
  unsigned int r = (v.u + 0x7FFFu + ((v.u >> 16) & 1u)) >> 16;
  return (u16)r;
}
__device__ __forceinline__ float b2f(u16 u) {
  union { unsigned int u; float f; } v; v.u = ((unsigned int)u) << 16;
  return v.f;
}
__device__ __forceinline__ float asf(unsigned u) {
  union { unsigned u; float f; } v; v.u = u; return v.f;
}

// ---------------------------------------------------------------------------
// prep + transpose fused (round-2/5 proven version).
// blk < 4096: transpose features2 [B][256][2048] f32 -> f2t [B][2048][256] bf16
// blk >= 4096: fold BN into alpha/beta; W1/W2 -> bf16 blocked [kt][o][32k]
// ---------------------------------------------------------------------------
__global__ void prep_transpose_kernel(
    const float* __restrict__ f2, u16* __restrict__ f2t,
    const float* __restrict__ w1, const float* __restrict__ b1,
    const float* __restrict__ g1, const float* __restrict__ be1,
    const float* __restrict__ m1, const float* __restrict__ v1,
    const float* __restrict__ w2, const float* __restrict__ b2,
    const float* __restrict__ g2, const float* __restrict__ be2,
    const float* __restrict__ m2, const float* __restrict__ v2,
    u16* __restrict__ w1b, u16* __restrict__ w2b,
    float* __restrict__ al1, float* __restrict__ bt1,
    float* __restrict__ al2, float* __restrict__ bt2) {
  __shared__ float tile[32][33];
  int t = threadIdx.x;
  int blk = blockIdx.x;
  if (blk < 4096) {
    int tx = t & 31, ty = t >> 5;        // ty in [0,8)
    int b = (blk >> 9) & 7;
    int n2t = (blk & 63) * 32, ct = ((blk >> 6) & 7) * 32;
#pragma unroll
    for (int i = 0; i < 4; ++i) {
      int c = ct + ty + i * 8;
      tile[ty + i * 8][tx] = f2[((size_t)b * 256 + c) * 2048 + n2t + tx];
    }
    __syncthreads();
#pragma unroll
    for (int i = 0; i < 4; ++i) {
      int n2 = n2t + ty + i * 8;
      f2t[((size_t)b * 2048 + n2) * 256 + ct + tx] = f2b(tile[tx][ty + i * 8]);
    }
  } else if (blk < 4480) {               // w1: 256x384
    int id = (blk - 4096) * 256 + t;
    unsigned o = (unsigned)id / 384u;
    unsigned c = (unsigned)id % 384u;
    w1b[(c >> 5) * 8192 + o * 32 + (c & 31)] = f2b(w1[id]);
  } else if (blk < 4736) {               // w2: 256x256
    int j = (blk - 4480) * 256 + t;
    unsigned o = (unsigned)j >> 8;
    unsigned c = (unsigned)j & 255u;
    w2b[(c >> 5) * 8192 + o * 32 + (c & 31)] = f2b(w2[j]);
  } else if (blk == 4736) {
    float a = g1[t] / sqrtf(v1[t] + BN_EPS);
    al1[t] = a;
    bt1[t] = (b1[t] - m1[t]) * a + be1[t];
  } else {
    float a = g2[t] / sqrtf(v2[t] + BN_EPS);
    al2[t] = a;
    bt2[t] = (b2[t] - m2[t]) * a + be2[t];
  }
}

// ---------------------------------------------------------------------------
// MEGA-FUSED: knn scan + interp + skip-copy + 2-layer GEMM, one block per
// panel (the former knn block p produced exactly the xb panel gemm block p
// consumed -> fuse, xb never touches HBM).
//  - scan/merge: verbatim R5 (LDS pts broadcast, gated insertion network)
//  - interp + f1 skip-tile write into LDS B-tile Bt[12][64][40] u16
//    (stride-40 pad = proven y1t pattern, 2-way-free on ds_read_b128)
//  - layer 1: A = w1b global depth-1 pipeline (L2-hot), B = Bt from LDS
//  - layer 2: unchanged (y1t in LDS union)
// LDS: Bt 61440 + union{pts+md+mi | f1t | y1t} 40960 + wts/idxs -> ~104 KB,
// 1 block/CU. All arithmetic expressions identical to R5 -> bit-identical.
// ---------------------------------------------------------------------------
__global__ __launch_bounds__(256) void fp_fused_kernel(
    const float* __restrict__ xyz1, const float* __restrict__ xyz2,
    const float* __restrict__ f1, const u16* __restrict__ f2t,
    const u16* __restrict__ w1b, const u16* __restrict__ w2b,
    const float* __restrict__ al1, const float* __restrict__ bt1,
    const float* __restrict__ al2, const float* __restrict__ bt2,
    float* __restrict__ fout) {
  union U {
    struct { float4 pts[2048]; float md[256 * 3]; u16 mi[256 * 3]; } a;  // 37376
    float f1t[128 * 65];                                                 // 33280
    u16 y1t[8 * 64 * 40];                                                // 40960
  };
  __shared__ U u;
  __shared__ u16 Bt[12 * 64 * 40];       // 61440 B, [kt][q][40-pad]
  __shared__ float wts[64 * 3];
  __shared__ int idxs[64 * 3];           // premultiplied by 256

  int t = threadIdx.x;
  int panel = blockIdx.x;                // = b*128 + tile
  int b = panel >> 7;
  int n1_0 = (panel & 127) * 64;

  // ---- phase 0: stage candidates (x,y,z,|x|^2) ----
  const float* x2 = xyz2 + b * 3 * 2048;
  for (int j = t; j < 2048; j += 256) {
    float cx = x2[j], cy = x2[2048 + j], cz = x2[4096 + j];
    float nsq = (cx * cx + cy * cy) + cz * cz;
    u.a.pts[j] = make_float4(cx, cy, cz, nsq);
  }
  __syncthreads();

  const float* x1 = xyz1 + b * 3 * 8192;

  // ---- phase 1: sliced top-3; lane = query, wave = slice ----
  {
    int p = t & 63, s = t >> 6;
    int n1 = n1_0 + p;
    float bx = x1[n1], by = x1[8192 + n1], bz = x1[16384 + n1];
    float nx = -2.f * bx, ny = -2.f * by, nz = -2.f * bz;
    float d0 = 3.4e38f, d1 = 3.4e38f, d2 = 3.4e38f;
    int i0 = 0, i1 = 0, i2 = 0;
    int jb = s * 512;

#define KNN_UPD(cv, jv)                                                      \
    {                                                                        \
      float sq = fmaf(nx, (cv).x, fmaf(ny, (cv).y, fmaf(nz, (cv).z, (cv).w))); \
      if (__any(sq < d2)) {                                                  \
        bool c0 = sq < d0, c1 = sq < d1, c2 = sq < d2;                       \
        i2 = c1 ? i1 : (c2 ? (jv) : i2);                                     \
        i1 = c0 ? i0 : (c1 ? (jv) : i1);                                     \
        i0 = c0 ? (jv) : i0;                                                 \
        d2 = __builtin_amdgcn_fmed3f(sq, d1, d2);                            \
        d1 = __builtin_amdgcn_fmed3f(sq, d0, d1);                            \
        d0 = fminf(sq, d0);                                                  \
      }                                                                      \
    }

    for (int jj = 0; jj < 512; jj += 4) {
      float4 ca = u.a.pts[jb + jj + 0];
      float4 cb = u.a.pts[jb + jj + 1];
      float4 cc = u.a.pts[jb + jj + 2];
      float4 cd = u.a.pts[jb + jj + 3];
      KNN_UPD(ca, jb + jj + 0);
      KNN_UPD(cb, jb + jj + 1);
      KNN_UPD(cc, jb + jj + 2);
      KNN_UPD(cd, jb + jj + 3);
    }
#undef KNN_UPD
    u.a.md[t * 3 + 0] = d0; u.a.md[t * 3 + 1] = d1; u.a.md[t * 3 + 2] = d2;
    u.a.mi[t * 3 + 0] = (u16)i0; u.a.mi[t * 3 + 1] = (u16)i1; u.a.mi[t * 3 + 2] = (u16)i2;
  }
  __syncthreads();
  if (t < 64) {
    // merge slices s=0..3 in ascending-index order (preserves tie-break)
    float d0 = 3.4e38f, d1 = 3.4e38f, d2 = 3.4e38f;
    int i0 = 0, i1 = 0, i2 = 0;
#pragma unroll
    for (int s = 0; s < 4; ++s) {
#pragma unroll
      for (int k = 0; k < 3; ++k) {
        float d = u.a.md[(s * 64 + t) * 3 + k];
        int i = (int)u.a.mi[(s * 64 + t) * 3 + k];
        bool c0 = d < d0, c1 = d < d1, c2 = d < d2;
        i2 = c1 ? i1 : (c2 ? i : i2);
        i1 = c0 ? i0 : (c1 ? i : i1);
        i0 = c0 ? i : i0;
        d2 = c1 ? d1 : (c2 ? d : d2);
        d1 = c0 ? d0 : (c1 ? d : d1);
        d0 = c0 ? d : d0;
      }
    }
    int n1 = n1_0 + t;
    float bx = x1[n1], by = x1[8192 + n1], bz = x1[16384 + n1];
    float nn = (bx * bx + by * by) + bz * bz;
    float e0 = fmaxf(d0 + nn, 1e-10f), e1 = fmaxf(d1 + nn, 1e-10f), e2 = fmaxf(d2 + nn, 1e-10f);
    float w0 = 1.0f / e0, w1 = 1.0f / e1, w2 = 1.0f / e2;
    float sm = (w0 + w1) + w2;
    wts[t * 3 + 0] = w0 / sm; wts[t * 3 + 1] = w1 / sm; wts[t * 3 + 2] = w2 / sm;
    idxs[t * 3 + 0] = i0 * 256; idxs[t * 3 + 1] = i1 * 256; idxs[t * 3 + 2] = i2 * 256;
  }
  __syncthreads();

  // ---- phase 2: interp -> Bt kt 0..7 (LDS), 64 channel-quads x 4 q-groups ----
  {
    const u16* f2tb = f2t + (size_t)b * 2048 * 256;
    int tc = t & 63;                     // channel quad: channels 4tc..4tc+3
    int qg = t >> 6;                     // query group (uniform per wave)
    int ce = (4 * tc) & 31;              // channel offset within 32-block
    int bbase = (tc >> 3) * 2560 + ce;   // kt*64*40 + ce
#pragma unroll 4
    for (int p2 = 0; p2 < 16; ++p2) {
      int p = p2 * 4 + qg;
      int j0 = idxs[p * 3 + 0], j1 = idxs[p * 3 + 1], j2 = idxs[p * 3 + 2];
      float w0 = wts[p * 3 + 0], w1 = wts[p * 3 + 1], w2 = wts[p * 3 + 2];
      uint2 a0 = *(const uint2*)&f2tb[j0 + 4 * tc];
      uint2 a1 = *(const uint2*)&f2tb[j1 + 4 * tc];
      uint2 a2 = *(const uint2*)&f2tb[j2 + 4 * tc];
      float v0 = (w0 * asf(a0.x << 16) + w1 * asf(a1.x << 16)) + w2 * asf(a2.x << 16);
      float v1 = (w0 * asf(a0.x & 0xffff0000u) + w1 * asf(a1.x & 0xffff0000u))
                 + w2 * asf(a2.x & 0xffff0000u);
      float v2 = (w0 * asf(a0.y << 16) + w1 * asf(a1.y << 16)) + w2 * asf(a2.y << 16);
      float v3 = (w0 * asf(a0.y & 0xffff0000u) + w1 * asf(a1.y & 0xffff0000u))
                 + w2 * asf(a2.y & 0xffff0000u);
      uint2 pk;
      pk.x = (unsigned)f2b(v0) | ((unsigned)f2b(v1) << 16);
      pk.y = (unsigned)f2b(v2) | ((unsigned)f2b(v3) << 16);
      *(uint2*)&Bt[bbase + p * 40] = pk;
    }
  }
  // no sync needed: phase 3 stage writes u.f1t (disjoint from wts/idxs/Bt)

  // ---- phase 3: skip features -> Bt kt 8..11 via LDS transpose ----
  {
    const float* f1b = f1 + (size_t)b * 128 * 8192 + n1_0;
    for (int it = 0; it < 32; ++it) {
      int c = it * 4 + (t >> 6);
      int n = t & 63;
      u.f1t[c * 65 + n] = f1b[(size_t)c * 8192 + n];
    }
    __syncthreads();
    for (int it = 0; it < 32; ++it) {
      int v = it * 256 + t;
      int c = v & 127, p = v >> 7;
      float val = u.f1t[c * 65 + p];
      Bt[(8 + (c >> 5)) * 2560 + p * 40 + (c & 31)] = f2b(val);
    }
  }
  __syncthreads();   // all Bt writes (interp + skip) visible; f1t reads done

  // ================= GEMM =================
  int w = t >> 6, lane = t & 63, l15 = lane & 15, quad = lane >> 4;

  f32x4 acc[4][4];
#pragma unroll
  for (int m = 0; m < 4; ++m)
#pragma unroll
    for (int n = 0; n < 4; ++n)
      acc[m][n] = (f32x4){0.f, 0.f, 0.f, 0.f};

  // ---- layer 1 K-loop (KT=12): A global depth-1 pipeline, B from Bt ----
  {
    const u16* aw = w1b + (size_t)(w * 64 + l15) * 32 + quad * 8;
    short8 af[2][4];
#pragma unroll
    for (int m = 0; m < 4; ++m)
      af[0][m] = *(const short8*)(aw + m * 512);
#pragma unroll
    for (int kt = 0; kt < 12; ++kt) {
      int cur = kt & 1, nxt = cur ^ 1;
      if (kt < 11) {
#pragma unroll
        for (int m = 0; m < 4; ++m)
          af[nxt][m] = *(const short8*)(aw + (kt + 1) * 8192 + m * 512);
      }
      short8 bf[4];
#pragma unroll
      for (int n = 0; n < 4; ++n)
        bf[n] = *(const short8*)&Bt[kt * 2560 + (n * 16 + l15) * 40 + quad * 8];
#pragma unroll
      for (int m = 0; m < 4; ++m)
#pragma unroll
        for (int n = 0; n < 4; ++n)
          acc[m][n] = __builtin_amdgcn_mfma_f32_16x16x32_bf16(af[cur][m], bf[n], acc[m][n], 0, 0, 0);
    }
  }

  // ---- epilogue 1: BN+ReLU -> bf16 -> y1t (blocked, stride 40) ----
  {
    float al[4][4], bt[4][4];
#pragma unroll
    for (int m = 0; m < 4; ++m)
#pragma unroll
      for (int r = 0; r < 4; ++r) {
        int o = w * 64 + m * 16 + quad * 4 + r;
        al[m][r] = al1[o];
        bt[m][r] = bt1[o];
      }
#pragma unroll
    for (int m = 0; m < 4; ++m) {
      int kt2 = w * 2 + (m >> 1);
      int osub = (m & 1) * 16 + quad * 4;
#pragma unroll
      for (int n = 0; n < 4; ++n) {
        int col = n * 16 + l15;
        ushort4 pk;
        pk.x = f2b(fmaxf(fmaf(al[m][0], acc[m][n][0], bt[m][0]), 0.f));
        pk.y = f2b(fmaxf(fmaf(al[m][1], acc[m][n][1], bt[m][1]), 0.f));
        pk.z = f2b(fmaxf(fmaf(al[m][2], acc[m][n][2], bt[m][2]), 0.f));
        pk.w = f2b(fmaxf(fmaf(al[m][3], acc[m][n][3], bt[m][3]), 0.f));
        *(ushort4*)&u.y1t[(kt2 * 64 + col) * 40 + osub] = pk;
      }
    }
  }
  __syncthreads();

  // ---- layer 2 K-loop (KT=8): A global (depth-1), B from y1t ----
#pragma unroll
  for (int m = 0; m < 4; ++m)
#pragma unroll
    for (int n = 0; n < 4; ++n)
      acc[m][n] = (f32x4){0.f, 0.f, 0.f, 0.f};
  {
    const u16* aw = w2b + (size_t)(w * 64 + l15) * 32 + quad * 8;
    short8 af[2][4];
#pragma unroll
    for (int m = 0; m < 4; ++m)
      af[0][m] = *(const short8*)(aw + m * 512);
#pragma unroll
    for (int kt = 0; kt < 8; ++kt) {
      int cur = kt & 1, nxt = cur ^ 1;
      if (kt < 7) {
#pragma unroll
        for (int m = 0; m < 4; ++m)
          af[nxt][m] = *(const short8*)(aw + (kt + 1) * 8192 + m * 512);
      }
      short8 bf[4];
#pragma unroll
      for (int n = 0; n < 4; ++n)
        bf[n] = *(const short8*)&u.y1t[(kt * 64 + n * 16 + l15) * 40 + quad * 8];
#pragma unroll
      for (int m = 0; m < 4; ++m)
#pragma unroll
        for (int n = 0; n < 4; ++n)
          acc[m][n] = __builtin_amdgcn_mfma_f32_16x16x32_bf16(af[cur][m], bf[n], acc[m][n], 0, 0, 0);
    }
  }

  // ---- epilogue 2: BN+ReLU -> f32 out [b][256][8192] ----
  {
    float al[4][4], bt[4][4];
#pragma unroll
    for (int m = 0; m < 4; ++m)
#pragma unroll
      for (int r = 0; r < 4; ++r) {
        int o = w * 64 + m * 16 + quad * 4 + r;
        al[m][r] = al2[o];
        bt[m][r] = bt2[o];
      }
#pragma unroll
    for (int m = 0; m < 4; ++m)
#pragma unroll
      for (int n = 0; n < 4; ++n) {
        int col = n * 16 + l15;
#pragma unroll
        for (int r = 0; r < 4; ++r) {
          int o = w * 64 + m * 16 + quad * 4 + r;
          float vv = fmaxf(fmaf(al[m][r], acc[m][n][r], bt[m][r]), 0.f);
          fout[(size_t)(b * 256 + o) * 8192 + n1_0 + col] = vv;
        }
      }
  }
}

// ---------------------------------------------------------------------------
// ws layout (bytes):
//   [50331648,   58720256)  f2t  bf16 [8][2048][256]               8 MB
//   [83886080,   84082688)  w1b  bf16 blocked
//   [84082688,   84213760)  w2b  bf16 blocked
//   [84213760,   84217856)  al1/bt1/al2/bt2 f32
// ---------------------------------------------------------------------------
extern "C" void kernel_launch(void* const* d_in, const int* in_sizes, int n_in,
                              void* d_out, int out_size, void* d_ws, size_t ws_size,
                              hipStream_t stream) {
  const float* xyz1 = (const float*)d_in[0];
  const float* xyz2 = (const float*)d_in[1];
  const float* f1   = (const float*)d_in[2];
  const float* f2   = (const float*)d_in[3];
  const float* w1   = (const float*)d_in[4];
  const float* b1   = (const float*)d_in[5];
  const float* g1   = (const float*)d_in[6];
  const float* be1  = (const float*)d_in[7];
  const float* m1   = (const float*)d_in[8];
  const float* v1   = (const float*)d_in[9];
  const float* w2   = (const float*)d_in[10];
  const float* b2   = (const float*)d_in[11];
  const float* g2   = (const float*)d_in[12];
  const float* be2  = (const float*)d_in[13];
  const float* m2   = (const float*)d_in[14];
  const float* v2   = (const float*)d_in[15];

  char* ws = (char*)d_ws;
  u16* f2t   = (u16*)(ws + 50331648);
  u16* w1b   = (u16*)(ws + 83886080);
  u16* w2b   = (u16*)(ws + 84082688);
  float* al1 = (float*)(ws + 84213760);
  float* bt1 = (float*)(ws + 84214784);
  float* al2 = (float*)(ws + 84215808);
  float* bt2 = (float*)(ws + 84216832);
  float* out = (float*)d_out;

  prep_transpose_kernel<<<4738, 256, 0, stream>>>(
      f2, f2t, w1, b1, g1, be1, m1, v1, w2, b2, g2, be2, m2, v2,
      w1b, w2b, al1, bt1, al2, bt2);
  fp_fused_kernel<<<1024, 256, 0, stream>>>(
      xyz1, xyz2, f1, f2t, w1b, w2b, al1, bt1, al2, bt2, out);
}

// Round 8
// 242.665 us; speedup vs baseline: 1.3025x; 1.3025x over previous
//
#include <hip/hip_runtime.h>
#include <hip/hip_bf16.h>

typedef unsigned short u16;
typedef __attribute__((ext_vector_type(4))) float f32x4;
typedef __attribute__((ext_vector_type(8))) short short8;

#define BN_EPS 1e-5f

__device__ __forceinline__ u16 f2b(float x) {
  union { float f; unsigned int u; } v; v.f = x;
  unsigned int r = (v.u + 0x7FFFu + ((v.u >> 16) & 1u)) >> 16;
  return (u16)r;
}
__device__ __forceinline__ float b2f(u16 u) {
  union { unsigned int u; float f; } v; v.u = ((unsigned int)u) << 16;
  return v.f;
}
__device__ __forceinline__ float asf(unsigned u) {
  union { unsigned u; float f; } v; v.u = u; return v.f;
}

// ---------------------------------------------------------------------------
// prep + transpose fused (round-2/5 proven version).
// blk < 4096: transpose features2 [B][256][2048] f32 -> f2t [B][2048][256] bf16
// blk >= 4096: fold BN into alpha/beta; W1/W2 -> bf16 blocked [kt][o][32k]
// ---------------------------------------------------------------------------
__global__ void prep_transpose_kernel(
    const float* __restrict__ f2, u16* __restrict__ f2t,
    const float* __restrict__ w1, const float* __restrict__ b1,
    const float* __restrict__ g1, const float* __restrict__ be1,
    const float* __restrict__ m1, const float* __restrict__ v1,
    const float* __restrict__ w2, const float* __restrict__ b2,
    const float* __restrict__ g2, const float* __restrict__ be2,
    const float* __restrict__ m2, const float* __restrict__ v2,
    u16* __restrict__ w1b, u16* __restrict__ w2b,
    float* __restrict__ al1, float* __restrict__ bt1,
    float* __restrict__ al2, float* __restrict__ bt2) {
  __shared__ float tile[32][33];
  int t = threadIdx.x;
  int blk = blockIdx.x;
  if (blk < 4096) {
    int tx = t & 31, ty = t >> 5;        // ty in [0,8)
    int b = (blk >> 9) & 7;
    int n2t = (blk & 63) * 32, ct = ((blk >> 6) & 7) * 32;
#pragma unroll
    for (int i = 0; i < 4; ++i) {
      int c = ct + ty + i * 8;
      tile[ty + i * 8][tx] = f2[((size_t)b * 256 + c) * 2048 + n2t + tx];
    }
    __syncthreads();
#pragma unroll
    for (int i = 0; i < 4; ++i) {
      int n2 = n2t + ty + i * 8;
      f2t[((size_t)b * 2048 + n2) * 256 + ct + tx] = f2b(tile[tx][ty + i * 8]);
    }
  } else if (blk < 4480) {               // w1: 256x384
    int id = (blk - 4096) * 256 + t;
    unsigned o = (unsigned)id / 384u;
    unsigned c = (unsigned)id % 384u;
    w1b[(c >> 5) * 8192 + o * 32 + (c & 31)] = f2b(w1[id]);
  } else if (blk < 4736) {               // w2: 256x256
    int j = (blk - 4480) * 256 + t;
    unsigned o = (unsigned)j >> 8;
    unsigned c = (unsigned)j & 255u;
    w2b[(c >> 5) * 8192 + o * 32 + (c & 31)] = f2b(w2[j]);
  } else if (blk == 4736) {
    float a = g1[t] / sqrtf(v1[t] + BN_EPS);
    al1[t] = a;
    bt1[t] = (b1[t] - m1[t]) * a + be1[t];
  } else {
    float a = g2[t] / sqrtf(v2[t] + BN_EPS);
    al2[t] = a;
    bt2[t] = (b2[t] - m2[t]) * a + be2[t];
  }
}

// ---------------------------------------------------------------------------
// knn + interp + skip-copy — R5 structure, but ONE BLOCK = TWO PANELS of the
// same batch: the two panels share the candidate set, so each lane carries
// TWO queries (qa = panel p0 col p, qb = panel p1 col p) and every
// ds_read_b128 feeds both insertion networks. Per-CU LDS-pipe work for the
// scan halves (the measured R5 bottleneck: 2048 reads/panel -> 1024).
// Distance expr / strict-< / med3-min update / ascending merge order are
// per-query identical to R5 -> selection bit-identical.
// ---------------------------------------------------------------------------
__global__ __launch_bounds__(256) void knn_interp_kernel(
    const float* __restrict__ xyz1, const float* __restrict__ xyz2,
    const float* __restrict__ f1, const u16* __restrict__ f2t,
    u16* __restrict__ xb) {
  union Lds {
    struct { float4 pts[2048]; float md[256 * 6]; u16 mi[256 * 6]; } a;  // 41984
    float f1t[64 * 129];                                                 // 33024
  };
  __shared__ Lds lds;
  __shared__ float wts[128 * 3];
  __shared__ int idxs[128 * 3];          // premultiplied by 256

  int t = threadIdx.x;
  int blk = blockIdx.x;                  // 512 blocks
  int b = blk >> 6;
  int tp = blk & 63;                     // tile pair
  int n1_0 = tp * 128;
  int p0 = b * 128 + tp * 2;             // first of the two panels

  // phase 0: stage candidates (x,y,z,|x|^2)
  const float* x2 = xyz2 + b * 3 * 2048;
  for (int j = t; j < 2048; j += 256) {
    float cx = x2[j], cy = x2[2048 + j], cz = x2[4096 + j];
    float nsq = (cx * cx + cy * cy) + cz * cz;
    lds.a.pts[j] = make_float4(cx, cy, cz, nsq);
  }
  __syncthreads();

  const float* x1 = xyz1 + b * 3 * 8192;

  // phase 1: sliced dual-query top-3; lane = col, wave = slice
  {
    int p = t & 63, s = t >> 6;
    int na = n1_0 + p;                   // panel p0 query
    int nb = n1_0 + 64 + p;              // panel p1 query
    float axq = x1[na], ayq = x1[8192 + na], azq = x1[16384 + na];
    float bxq = x1[nb], byq = x1[8192 + nb], bzq = x1[16384 + nb];
    float nxa = -2.f * axq, nya = -2.f * ayq, nza = -2.f * azq;
    float nxb = -2.f * bxq, nyb = -2.f * byq, nzb = -2.f * bzq;
    // comparator value: sq' = |c|^2 - 2 q.c  (biased by -|q|^2, rank-equal)
    float da0 = 3.4e38f, da1 = 3.4e38f, da2 = 3.4e38f;
    float db0 = 3.4e38f, db1 = 3.4e38f, db2 = 3.4e38f;
    int ia0 = 0, ia1 = 0, ia2 = 0, ib0 = 0, ib1 = 0, ib2 = 0;
    int jb = s * 512;

#define KNN_UPD2(cv, jv)                                                     \
    {                                                                        \
      float sqa = fmaf(nxa, (cv).x, fmaf(nya, (cv).y, fmaf(nza, (cv).z, (cv).w))); \
      float sqb = fmaf(nxb, (cv).x, fmaf(nyb, (cv).y, fmaf(nzb, (cv).z, (cv).w))); \
      if (__any((sqa < da2) || (sqb < db2))) {                               \
        bool a0 = sqa < da0, a1 = sqa < da1, a2 = sqa < da2;                 \
        ia2 = a1 ? ia1 : (a2 ? (jv) : ia2);                                  \
        ia1 = a0 ? ia0 : (a1 ? (jv) : ia1);                                  \
        ia0 = a0 ? (jv) : ia0;                                               \
        da2 = __builtin_amdgcn_fmed3f(sqa, da1, da2);                        \
        da1 = __builtin_amdgcn_fmed3f(sqa, da0, da1);                        \
        da0 = fminf(sqa, da0);                                               \
        bool b0 = sqb < db0, b1 = sqb < db1, b2 = sqb < db2;                 \
        ib2 = b1 ? ib1 : (b2 ? (jv) : ib2);                                  \
        ib1 = b0 ? ib0 : (b1 ? (jv) : ib1);                                  \
        ib0 = b0 ? (jv) : ib0;                                               \
        db2 = __builtin_amdgcn_fmed3f(sqb, db1, db2);                        \
        db1 = __builtin_amdgcn_fmed3f(sqb, db0, db1);                        \
        db0 = fminf(sqb, db0);                                               \
      }                                                                      \
    }

    for (int jj = 0; jj < 512; jj += 4) {
      float4 ca = lds.a.pts[jb + jj + 0];
      float4 cb = lds.a.pts[jb + jj + 1];
      float4 cc = lds.a.pts[jb + jj + 2];
      float4 cd = lds.a.pts[jb + jj + 3];
      KNN_UPD2(ca, jb + jj + 0);
      KNN_UPD2(cb, jb + jj + 1);
      KNN_UPD2(cc, jb + jj + 2);
      KNN_UPD2(cd, jb + jj + 3);
    }
#undef KNN_UPD2
    lds.a.md[t * 6 + 0] = da0; lds.a.md[t * 6 + 1] = da1; lds.a.md[t * 6 + 2] = da2;
    lds.a.md[t * 6 + 3] = db0; lds.a.md[t * 6 + 4] = db1; lds.a.md[t * 6 + 5] = db2;
    lds.a.mi[t * 6 + 0] = (u16)ia0; lds.a.mi[t * 6 + 1] = (u16)ia1; lds.a.mi[t * 6 + 2] = (u16)ia2;
    lds.a.mi[t * 6 + 3] = (u16)ib0; lds.a.mi[t * 6 + 4] = (u16)ib1; lds.a.mi[t * 6 + 5] = (u16)ib2;
  }
  __syncthreads();
  if (t < 128) {
    // merge slices s=0..3 in ascending-index order (preserves tie-break)
    int p = t & 63, side = t >> 6;       // query t = n1_0 + t
    float d0 = 3.4e38f, d1 = 3.4e38f, d2 = 3.4e38f;
    int i0 = 0, i1 = 0, i2 = 0;
#pragma unroll
    for (int s = 0; s < 4; ++s) {
#pragma unroll
      for (int k = 0; k < 3; ++k) {
        float d = lds.a.md[(s * 64 + p) * 6 + side * 3 + k];
        int i = (int)lds.a.mi[(s * 64 + p) * 6 + side * 3 + k];
        bool c0 = d < d0, c1 = d < d1, c2 = d < d2;
        i2 = c1 ? i1 : (c2 ? i : i2);
        i1 = c0 ? i0 : (c1 ? i : i1);
        i0 = c0 ? i : i0;
        d2 = c1 ? d1 : (c2 ? d : d2);
        d1 = c0 ? d0 : (c1 ? d : d1);
        d0 = c0 ? d : d0;
      }
    }
    // un-bias: recompute |q|^2 for this query (3 L1-hot loads)
    int n1 = n1_0 + t;
    float bx = x1[n1], by = x1[8192 + n1], bz = x1[16384 + n1];
    float nn = (bx * bx + by * by) + bz * bz;
    float e0 = fmaxf(d0 + nn, 1e-10f), e1 = fmaxf(d1 + nn, 1e-10f), e2 = fmaxf(d2 + nn, 1e-10f);
    float w0 = 1.0f / e0, w1 = 1.0f / e1, w2 = 1.0f / e2;
    float sm = (w0 + w1) + w2;
    wts[t * 3 + 0] = w0 / sm; wts[t * 3 + 1] = w1 / sm; wts[t * 3 + 2] = w2 / sm;
    idxs[t * 3 + 0] = i0 * 256; idxs[t * 3 + 1] = i1 * 256; idxs[t * 3 + 2] = i2 * 256;
  }
  __syncthreads();

  // phase 2: interp 256 channels as 64 channel-quads x 4 query groups,
  // 128 queries (2 panels)
  {
    const u16* f2tb = f2t + (size_t)b * 2048 * 256;
    int tc = t & 63;                     // channel quad: channels 4tc..4tc+3
    int qg = t >> 6;                     // query group (uniform per wave)
    int ce = (4 * tc) & 31;              // channel offset within 32-block
    int ktoff = (tc >> 3) * 2048 + ce;
#pragma unroll 4
    for (int p2 = 0; p2 < 32; ++p2) {
      int p = p2 * 4 + qg;               // query 0..127
      int j0 = idxs[p * 3 + 0], j1 = idxs[p * 3 + 1], j2 = idxs[p * 3 + 2];
      float w0 = wts[p * 3 + 0], w1 = wts[p * 3 + 1], w2 = wts[p * 3 + 2];
      uint2 a0 = *(const uint2*)&f2tb[j0 + 4 * tc];
      uint2 a1 = *(const uint2*)&f2tb[j1 + 4 * tc];
      uint2 a2 = *(const uint2*)&f2tb[j2 + 4 * tc];
      float v0 = (w0 * asf(a0.x << 16) + w1 * asf(a1.x << 16)) + w2 * asf(a2.x << 16);
      float v1 = (w0 * asf(a0.x & 0xffff0000u) + w1 * asf(a1.x & 0xffff0000u))
                 + w2 * asf(a2.x & 0xffff0000u);
      float v2 = (w0 * asf(a0.y << 16) + w1 * asf(a1.y << 16)) + w2 * asf(a2.y << 16);
      float v3 = (w0 * asf(a0.y & 0xffff0000u) + w1 * asf(a1.y & 0xffff0000u))
                 + w2 * asf(a2.y & 0xffff0000u);
      uint2 pk;
      pk.x = (unsigned)f2b(v0) | ((unsigned)f2b(v1) << 16);
      pk.y = (unsigned)f2b(v2) | ((unsigned)f2b(v3) << 16);
      size_t xaddr = (size_t)(p0 + (p >> 6)) * 24576 + ktoff + (size_t)(p & 63) * 32;
      *(uint2*)&xb[xaddr] = pk;
    }
  }

  // phase 3: skip features (channels 256..383) for BOTH panels, two
  // 64-channel halves through the 64x129 f1t buffer.
  {
    const float* f1b = f1 + (size_t)b * 128 * 8192 + n1_0;
#pragma unroll
    for (int h = 0; h < 2; ++h) {
      __syncthreads();                   // previous reads of lds done
      for (int it = 0; it < 32; ++it) {
        int c = it * 2 + (t >> 7);       // 0..63
        int n = t & 127;                 // 0..127
        lds.f1t[c * 129 + n] = f1b[(size_t)(h * 64 + c) * 8192 + n];
      }
      __syncthreads();
      for (int it = 0; it < 32; ++it) {
        int v = it * 256 + t;
        int c = v & 63, p = v >> 6;      // c: 0..63, p: 0..127
        int ch = h * 64 + c;
        float val = lds.f1t[c * 129 + p];
        size_t xaddr = (size_t)(p0 + (p >> 6)) * 24576
                     + (size_t)(8 + (ch >> 5)) * 2048
                     + (size_t)(p & 63) * 32 + (ch & 31);
        xb[xaddr] = f2b(val);
      }
    }
  }
}

// ---------------------------------------------------------------------------
// FUSED 2-layer GEMM with explicit depth-1 register software pipeline.
// (unchanged round-2/5 version)
// ---------------------------------------------------------------------------
__global__ __launch_bounds__(256) void gemm_fused_kernel(
    const u16* __restrict__ xin, const u16* __restrict__ w1b,
    const u16* __restrict__ w2b,
    const float* __restrict__ al1, const float* __restrict__ bt1,
    const float* __restrict__ al2, const float* __restrict__ bt2,
    float* __restrict__ fout) {
  __shared__ u16 y1t[8 * 64 * 40];       // 40960 B
  int t = threadIdx.x;
  int panel = blockIdx.x;
  int w = t >> 6, lane = t & 63, l15 = lane & 15, quad = lane >> 4;

  f32x4 acc[4][4];
#pragma unroll
  for (int m = 0; m < 4; ++m)
#pragma unroll
    for (int n = 0; n < 4; ++n)
      acc[m][n] = (f32x4){0.f, 0.f, 0.f, 0.f};

  // ---- layer 1 K-loop (KT=12), depth-1 register pipeline ----
  {
    const u16* aw = w1b + (size_t)(w * 64 + l15) * 32 + quad * 8;
    const u16* bx = xin + (size_t)panel * 24576 + (size_t)l15 * 32 + quad * 8;
    short8 af[2][4], bf[2][4];
#pragma unroll
    for (int m = 0; m < 4; ++m)
      af[0][m] = *(const short8*)(aw + m * 512);
#pragma unroll
    for (int n = 0; n < 4; ++n)
      bf[0][n] = *(const short8*)(bx + n * 512);
#pragma unroll
    for (int kt = 0; kt < 12; ++kt) {
      int cur = kt & 1, nxt = cur ^ 1;
      if (kt < 11) {
#pragma unroll
        for (int m = 0; m < 4; ++m)
          af[nxt][m] = *(const short8*)(aw + (kt + 1) * 8192 + m * 512);
#pragma unroll
        for (int n = 0; n < 4; ++n)
          bf[nxt][n] = *(const short8*)(bx + (kt + 1) * 2048 + n * 512);
      }
#pragma unroll
      for (int m = 0; m < 4; ++m)
#pragma unroll
        for (int n = 0; n < 4; ++n)
          acc[m][n] = __builtin_amdgcn_mfma_f32_16x16x32_bf16(af[cur][m], bf[cur][n], acc[m][n], 0, 0, 0);
    }
  }

  // ---- epilogue 1: BN+ReLU -> bf16 -> LDS y1 tile (blocked, stride 40) ----
  {
    float al[4][4], bt[4][4];
#pragma unroll
    for (int m = 0; m < 4; ++m)
#pragma unroll
      for (int r = 0; r < 4; ++r) {
        int o = w * 64 + m * 16 + quad * 4 + r;
        al[m][r] = al1[o];
        bt[m][r] = bt1[o];
      }
#pragma unroll
    for (int m = 0; m < 4; ++m) {
      int kt2 = w * 2 + (m >> 1);
      int osub = (m & 1) * 16 + quad * 4;
#pragma unroll
      for (int n = 0; n < 4; ++n) {
        int col = n * 16 + l15;
        ushort4 pk;
        pk.x = f2b(fmaxf(fmaf(al[m][0], acc[m][n][0], bt[m][0]), 0.f));
        pk.y = f2b(fmaxf(fmaf(al[m][1], acc[m][n][1], bt[m][1]), 0.f));
        pk.z = f2b(fmaxf(fmaf(al[m][2], acc[m][n][2], bt[m][2]), 0.f));
        pk.w = f2b(fmaxf(fmaf(al[m][3], acc[m][n][3], bt[m][3]), 0.f));
        *(ushort4*)&y1t[(kt2 * 64 + col) * 40 + osub] = pk;
      }
    }
  }
  __syncthreads();

  // ---- layer 2 K-loop (KT=8): A global (depth-1 pipeline), B from LDS ----
#pragma unroll
  for (int m = 0; m < 4; ++m)
#pragma unroll
    for (int n = 0; n < 4; ++n)
      acc[m][n] = (f32x4){0.f, 0.f, 0.f, 0.f};
  {
    const u16* aw = w2b + (size_t)(w * 64 + l15) * 32 + quad * 8;
    short8 af[2][4];
#pragma unroll
    for (int m = 0; m < 4; ++m)
      af[0][m] = *(const short8*)(aw + m * 512);
#pragma unroll
    for (int kt = 0; kt < 8; ++kt) {
      int cur = kt & 1, nxt = cur ^ 1;
      if (kt < 7) {
#pragma unroll
        for (int m = 0; m < 4; ++m)
          af[nxt][m] = *(const short8*)(aw + (kt + 1) * 8192 + m * 512);
      }
      short8 bf[4];
#pragma unroll
      for (int n = 0; n < 4; ++n)
        bf[n] = *(const short8*)&y1t[(kt * 64 + n * 16 + l15) * 40 + quad * 8];
#pragma unroll
      for (int m = 0; m < 4; ++m)
#pragma unroll
        for (int n = 0; n < 4; ++n)
          acc[m][n] = __builtin_amdgcn_mfma_f32_16x16x32_bf16(af[cur][m], bf[n], acc[m][n], 0, 0, 0);
    }
  }

  // ---- epilogue 2: BN+ReLU -> f32 out [b][256][8192] ----
  {
    float al[4][4], bt[4][4];
#pragma unroll
    for (int m = 0; m < 4; ++m)
#pragma unroll
      for (int r = 0; r < 4; ++r) {
        int o = w * 64 + m * 16 + quad * 4 + r;
        al[m][r] = al2[o];
        bt[m][r] = bt2[o];
      }
    int bb = panel >> 7;
    int n1base = (panel & 127) * 64;
#pragma unroll
    for (int m = 0; m < 4; ++m)
#pragma unroll
      for (int n = 0; n < 4; ++n) {
        int col = n * 16 + l15;
#pragma unroll
        for (int r = 0; r < 4; ++r) {
          int o = w * 64 + m * 16 + quad * 4 + r;
          float vv = fmaxf(fmaf(al[m][r], acc[m][n][r], bt[m][r]), 0.f);
          fout[(size_t)(bb * 256 + o) * 8192 + n1base + col] = vv;
        }
      }
  }
}

// ---------------------------------------------------------------------------
// ws layout (bytes):
//   [0,          50331648)  xb   bf16 [1024 panels][12][64][32]   48 MB
//   [50331648,   58720256)  f2t  bf16 [8][2048][256]               8 MB
//   [83886080,   84082688)  w1b  bf16 blocked
//   [84082688,   84213760)  w2b  bf16 blocked
//   [84213760,   84217856)  al1/bt1/al2/bt2 f32
// ---------------------------------------------------------------------------
extern "C" void kernel_launch(void* const* d_in, const int* in_sizes, int n_in,
                              void* d_out, int out_size, void* d_ws, size_t ws_size,
                              hipStream_t stream) {
  const float* xyz1 = (const float*)d_in[0];
  const float* xyz2 = (const float*)d_in[1];
  const float* f1   = (const float*)d_in[2];
  const float* f2   = (const float*)d_in[3];
  const float* w1   = (const float*)d_in[4];
  const float* b1   = (const float*)d_in[5];
  const float* g1   = (const float*)d_in[6];
  const float* be1  = (const float*)d_in[7];
  const float* m1   = (const float*)d_in[8];
  const float* v1   = (const float*)d_in[9];
  const float* w2   = (const float*)d_in[10];
  const float* b2   = (const float*)d_in[11];
  const float* g2   = (const float*)d_in[12];
  const float* be2  = (const float*)d_in[13];
  const float* m2   = (const float*)d_in[14];
  const float* v2   = (const float*)d_in[15];

  char* ws = (char*)d_ws;
  u16* xb   = (u16*)(ws);
  u16* f2t  = (u16*)(ws + 50331648);
  u16* w1b  = (u16*)(ws + 83886080);
  u16* w2b  = (u16*)(ws + 84082688);
  float* al1 = (float*)(ws + 84213760);
  float* bt1 = (float*)(ws + 84214784);
  float* al2 = (float*)(ws + 84215808);
  float* bt2 = (float*)(ws + 84216832);
  float* out = (float*)d_out;

  prep_transpose_kernel<<<4738, 256, 0, stream>>>(
      f2, f2t, w1, b1, g1, be1, m1, v1, w2, b2, g2, be2, m2, v2,
      w1b, w2b, al1, bt1, al2, bt2);
  knn_interp_kernel<<<512, 256, 0, stream>>>(xyz1, xyz2, f1, f2t, xb);
  gemm_fused_kernel<<<1024, 256, 0, stream>>>(xb, w1b, w2b, al1, bt1, al2, bt2, out);
}

// Round 9
// 235.716 us; speedup vs baseline: 1.3409x; 1.0295x over previous
//
#include <hip/hip_runtime.h>
#include <hip/hip_bf16.h>

typedef unsigned short u16;
typedef __attribute__((ext_vector_type(4))) float f32x4;
typedef __attribute__((ext_vector_type(8))) short short8;

#define BN_EPS 1e-5f

__device__ __forceinline__ u16 f2b(float x) {
  union { float f; unsigned int u; } v; v.f = x;
  unsigned int r = (v.u + 0x7FFFu + ((v.u >> 16) & 1u)) >> 16;
  return (u16)r;
}
__device__ __forceinline__ float b2f(u16 u) {
  union { unsigned int u; float f; } v; v.u = ((unsigned int)u) << 16;
  return v.f;
}
__device__ __forceinline__ float asf(unsigned u) {
  union { unsigned u; float f; } v; v.u = u; return v.f;
}

// ---------------------------------------------------------------------------
// prep + transpose fused (round-2/5 proven version).
// ---------------------------------------------------------------------------
__global__ void prep_transpose_kernel(
    const float* __restrict__ f2, u16* __restrict__ f2t,
    const float* __restrict__ w1, const float* __restrict__ b1,
    const float* __restrict__ g1, const float* __restrict__ be1,
    const float* __restrict__ m1, const float* __restrict__ v1,
    const float* __restrict__ w2, const float* __restrict__ b2,
    const float* __restrict__ g2, const float* __restrict__ be2,
    const float* __restrict__ m2, const float* __restrict__ v2,
    u16* __restrict__ w1b, u16* __restrict__ w2b,
    float* __restrict__ al1, float* __restrict__ bt1,
    float* __restrict__ al2, float* __restrict__ bt2) {
  __shared__ float tile[32][33];
  int t = threadIdx.x;
  int blk = blockIdx.x;
  if (blk < 4096) {
    int tx = t & 31, ty = t >> 5;        // ty in [0,8)
    int b = (blk >> 9) & 7;
    int n2t = (blk & 63) * 32, ct = ((blk >> 6) & 7) * 32;
#pragma unroll
    for (int i = 0; i < 4; ++i) {
      int c = ct + ty + i * 8;
      tile[ty + i * 8][tx] = f2[((size_t)b * 256 + c) * 2048 + n2t + tx];
    }
    __syncthreads();
#pragma unroll
    for (int i = 0; i < 4; ++i) {
      int n2 = n2t + ty + i * 8;
      f2t[((size_t)b * 2048 + n2) * 256 + ct + tx] = f2b(tile[tx][ty + i * 8]);
    }
  } else if (blk < 4480) {               // w1: 256x384
    int id = (blk - 4096) * 256 + t;
    unsigned o = (unsigned)id / 384u;
    unsigned c = (unsigned)id % 384u;
    w1b[(c >> 5) * 8192 + o * 32 + (c & 31)] = f2b(w1[id]);
  } else if (blk < 4736) {               // w2: 256x256
    int j = (blk - 4480) * 256 + t;
    unsigned o = (unsigned)j >> 8;
    unsigned c = (unsigned)j & 255u;
    w2b[(c >> 5) * 8192 + o * 32 + (c & 31)] = f2b(w2[j]);
  } else if (blk == 4736) {
    float a = g1[t] / sqrtf(v1[t] + BN_EPS);
    al1[t] = a;
    bt1[t] = (b1[t] - m1[t]) * a + be1[t];
  } else {
    float a = g2[t] / sqrtf(v2[t] + BN_EPS);
    al2[t] = a;
    bt2[t] = (b2[t] - m2[t]) * a + be2[t];
  }
}

// ---------------------------------------------------------------------------
// knn + interp + skip-copy — R8's dual-panel scan (semantics proven) with
// FIXED launch geometry: 512-thread blocks (8 waves), 512 blocks
// -> 2 blocks/CU x 8 waves = 16 waves/CU = 4/SIMD (R5's TLP), while per-CU
// scan ds_read count stays HALVED (2 blocks x 2048 = 4096 vs R5's 8192).
// Slices: 8 waves x 256 candidates; merge in ascending s preserves the
// ascending-index tie-break -> selection bit-identical.
// ---------------------------------------------------------------------------
__global__ __launch_bounds__(512) void knn_interp_kernel(
    const float* __restrict__ xyz1, const float* __restrict__ xyz2,
    const float* __restrict__ f1, const u16* __restrict__ f2t,
    u16* __restrict__ xb) {
  union Lds {
    struct { float4 pts[2048]; float md[512 * 6]; u16 mi[512 * 6]; } a;  // 51200
    float f1t[64 * 129];                                                 // 33024
  };
  __shared__ Lds lds;
  __shared__ float wts[128 * 3];
  __shared__ int idxs[128 * 3];          // premultiplied by 256

  int t = threadIdx.x;                   // 0..511
  int blk = blockIdx.x;                  // 512 blocks
  int b = blk >> 6;
  int tp = blk & 63;                     // tile pair
  int n1_0 = tp * 128;
  int p0 = b * 128 + tp * 2;             // first of the two panels

  // phase 0: stage candidates (x,y,z,|x|^2)
  const float* x2 = xyz2 + b * 3 * 2048;
  for (int j = t; j < 2048; j += 512) {
    float cx = x2[j], cy = x2[2048 + j], cz = x2[4096 + j];
    float nsq = (cx * cx + cy * cy) + cz * cz;
    lds.a.pts[j] = make_float4(cx, cy, cz, nsq);
  }
  __syncthreads();

  const float* x1 = xyz1 + b * 3 * 8192;

  // phase 1: sliced dual-query top-3; lane = col, wave = slice (8 x 256)
  {
    int p = t & 63, s = t >> 6;          // s in [0,8)
    int na = n1_0 + p;                   // panel p0 query
    int nb = n1_0 + 64 + p;              // panel p1 query
    float axq = x1[na], ayq = x1[8192 + na], azq = x1[16384 + na];
    float bxq = x1[nb], byq = x1[8192 + nb], bzq = x1[16384 + nb];
    float nxa = -2.f * axq, nya = -2.f * ayq, nza = -2.f * azq;
    float nxb = -2.f * bxq, nyb = -2.f * byq, nzb = -2.f * bzq;
    // comparator value: sq' = |c|^2 - 2 q.c  (biased by -|q|^2, rank-equal)
    float da0 = 3.4e38f, da1 = 3.4e38f, da2 = 3.4e38f;
    float db0 = 3.4e38f, db1 = 3.4e38f, db2 = 3.4e38f;
    int ia0 = 0, ia1 = 0, ia2 = 0, ib0 = 0, ib1 = 0, ib2 = 0;
    int jb = s * 256;

#define KNN_UPD2(cv, jv)                                                     \
    {                                                                        \
      float sqa = fmaf(nxa, (cv).x, fmaf(nya, (cv).y, fmaf(nza, (cv).z, (cv).w))); \
      float sqb = fmaf(nxb, (cv).x, fmaf(nyb, (cv).y, fmaf(nzb, (cv).z, (cv).w))); \
      if (__any((sqa < da2) || (sqb < db2))) {                               \
        bool a0 = sqa < da0, a1 = sqa < da1, a2 = sqa < da2;                 \
        ia2 = a1 ? ia1 : (a2 ? (jv) : ia2);                                  \
        ia1 = a0 ? ia0 : (a1 ? (jv) : ia1);                                  \
        ia0 = a0 ? (jv) : ia0;                                               \
        da2 = __builtin_amdgcn_fmed3f(sqa, da1, da2);                        \
        da1 = __builtin_amdgcn_fmed3f(sqa, da0, da1);                        \
        da0 = fminf(sqa, da0);                                               \
        bool b0 = sqb < db0, b1 = sqb < db1, b2 = sqb < db2;                 \
        ib2 = b1 ? ib1 : (b2 ? (jv) : ib2);                                  \
        ib1 = b0 ? ib0 : (b1 ? (jv) : ib1);                                  \
        ib0 = b0 ? (jv) : ib0;                                               \
        db2 = __builtin_amdgcn_fmed3f(sqb, db1, db2);                        \
        db1 = __builtin_amdgcn_fmed3f(sqb, db0, db1);                        \
        db0 = fminf(sqb, db0);                                               \
      }                                                                      \
    }

    for (int jj = 0; jj < 256; jj += 4) {
      float4 ca = lds.a.pts[jb + jj + 0];
      float4 cb = lds.a.pts[jb + jj + 1];
      float4 cc = lds.a.pts[jb + jj + 2];
      float4 cd = lds.a.pts[jb + jj + 3];
      KNN_UPD2(ca, jb + jj + 0);
      KNN_UPD2(cb, jb + jj + 1);
      KNN_UPD2(cc, jb + jj + 2);
      KNN_UPD2(cd, jb + jj + 3);
    }
#undef KNN_UPD2
    lds.a.md[t * 6 + 0] = da0; lds.a.md[t * 6 + 1] = da1; lds.a.md[t * 6 + 2] = da2;
    lds.a.md[t * 6 + 3] = db0; lds.a.md[t * 6 + 4] = db1; lds.a.md[t * 6 + 5] = db2;
    lds.a.mi[t * 6 + 0] = (u16)ia0; lds.a.mi[t * 6 + 1] = (u16)ia1; lds.a.mi[t * 6 + 2] = (u16)ia2;
    lds.a.mi[t * 6 + 3] = (u16)ib0; lds.a.mi[t * 6 + 4] = (u16)ib1; lds.a.mi[t * 6 + 5] = (u16)ib2;
  }
  __syncthreads();
  if (t < 128) {
    // merge slices s=0..7 in ascending-index order (preserves tie-break)
    int p = t & 63, side = t >> 6;       // query t = n1_0 + t
    float d0 = 3.4e38f, d1 = 3.4e38f, d2 = 3.4e38f;
    int i0 = 0, i1 = 0, i2 = 0;
#pragma unroll
    for (int s = 0; s < 8; ++s) {
#pragma unroll
      for (int k = 0; k < 3; ++k) {
        float d = lds.a.md[(s * 64 + p) * 6 + side * 3 + k];
        int i = (int)lds.a.mi[(s * 64 + p) * 6 + side * 3 + k];
        bool c0 = d < d0, c1 = d < d1, c2 = d < d2;
        i2 = c1 ? i1 : (c2 ? i : i2);
        i1 = c0 ? i0 : (c1 ? i : i1);
        i0 = c0 ? i : i0;
        d2 = c1 ? d1 : (c2 ? d : d2);
        d1 = c0 ? d0 : (c1 ? d : d1);
        d0 = c0 ? d : d0;
      }
    }
    // un-bias: recompute |q|^2 for this query (3 L1-hot loads)
    int n1 = n1_0 + t;
    float bx = x1[n1], by = x1[8192 + n1], bz = x1[16384 + n1];
    float nn = (bx * bx + by * by) + bz * bz;
    float e0 = fmaxf(d0 + nn, 1e-10f), e1 = fmaxf(d1 + nn, 1e-10f), e2 = fmaxf(d2 + nn, 1e-10f);
    float w0 = 1.0f / e0, w1 = 1.0f / e1, w2 = 1.0f / e2;
    float sm = (w0 + w1) + w2;
    wts[t * 3 + 0] = w0 / sm; wts[t * 3 + 1] = w1 / sm; wts[t * 3 + 2] = w2 / sm;
    idxs[t * 3 + 0] = i0 * 256; idxs[t * 3 + 1] = i1 * 256; idxs[t * 3 + 2] = i2 * 256;
  }
  __syncthreads();

  // phase 2: interp 256 channels as 64 channel-quads x 8 query groups,
  // 128 queries (2 panels)
  {
    const u16* f2tb = f2t + (size_t)b * 2048 * 256;
    int tc = t & 63;                     // channel quad: channels 4tc..4tc+3
    int qg = t >> 6;                     // query group 0..7 (uniform per wave)
    int ce = (4 * tc) & 31;              // channel offset within 32-block
    int ktoff = (tc >> 3) * 2048 + ce;
#pragma unroll 4
    for (int p2 = 0; p2 < 16; ++p2) {
      int p = p2 * 8 + qg;               // query 0..127
      int j0 = idxs[p * 3 + 0], j1 = idxs[p * 3 + 1], j2 = idxs[p * 3 + 2];
      float w0 = wts[p * 3 + 0], w1 = wts[p * 3 + 1], w2 = wts[p * 3 + 2];
      uint2 a0 = *(const uint2*)&f2tb[j0 + 4 * tc];
      uint2 a1 = *(const uint2*)&f2tb[j1 + 4 * tc];
      uint2 a2 = *(const uint2*)&f2tb[j2 + 4 * tc];
      float v0 = (w0 * asf(a0.x << 16) + w1 * asf(a1.x << 16)) + w2 * asf(a2.x << 16);
      float v1 = (w0 * asf(a0.x & 0xffff0000u) + w1 * asf(a1.x & 0xffff0000u))
                 + w2 * asf(a2.x & 0xffff0000u);
      float v2 = (w0 * asf(a0.y << 16) + w1 * asf(a1.y << 16)) + w2 * asf(a2.y << 16);
      float v3 = (w0 * asf(a0.y & 0xffff0000u) + w1 * asf(a1.y & 0xffff0000u))
                 + w2 * asf(a2.y & 0xffff0000u);
      uint2 pk;
      pk.x = (unsigned)f2b(v0) | ((unsigned)f2b(v1) << 16);
      pk.y = (unsigned)f2b(v2) | ((unsigned)f2b(v3) << 16);
      size_t xaddr = (size_t)(p0 + (p >> 6)) * 24576 + ktoff + (size_t)(p & 63) * 32;
      *(uint2*)&xb[xaddr] = pk;
    }
  }

  // phase 3: skip features (channels 256..383) for BOTH panels, two
  // 64-channel halves through the 64x129 f1t buffer.
  {
    const float* f1b = f1 + (size_t)b * 128 * 8192 + n1_0;
#pragma unroll
    for (int h = 0; h < 2; ++h) {
      __syncthreads();                   // previous reads of lds done
      for (int it = 0; it < 16; ++it) {
        int c = it * 4 + (t >> 7);       // 0..63
        int n = t & 127;                 // 0..127
        lds.f1t[c * 129 + n] = f1b[(size_t)(h * 64 + c) * 8192 + n];
      }
      __syncthreads();
      for (int it = 0; it < 16; ++it) {
        int v = it * 512 + t;
        int c = v & 63, p = v >> 6;      // c: 0..63, p: 0..127
        int ch = h * 64 + c;
        float val = lds.f1t[c * 129 + p];
        size_t xaddr = (size_t)(p0 + (p >> 6)) * 24576
                     + (size_t)(8 + (ch >> 5)) * 2048
                     + (size_t)(p & 63) * 32 + (ch & 31);
        xb[xaddr] = f2b(val);
      }
    }
  }
}

// ---------------------------------------------------------------------------
// FUSED 2-layer GEMM with explicit depth-1 register software pipeline.
// (unchanged round-2/5 version)
// ---------------------------------------------------------------------------
__global__ __launch_bounds__(256) void gemm_fused_kernel(
    const u16* __restrict__ xin, const u16* __restrict__ w1b,
    const u16* __restrict__ w2b,
    const float* __restrict__ al1, const float* __restrict__ bt1,
    const float* __restrict__ al2, const float* __restrict__ bt2,
    float* __restrict__ fout) {
  __shared__ u16 y1t[8 * 64 * 40];       // 40960 B
  int t = threadIdx.x;
  int panel = blockIdx.x;
  int w = t >> 6, lane = t & 63, l15 = lane & 15, quad = lane >> 4;

  f32x4 acc[4][4];
#pragma unroll
  for (int m = 0; m < 4; ++m)
#pragma unroll
    for (int n = 0; n < 4; ++n)
      acc[m][n] = (f32x4){0.f, 0.f, 0.f, 0.f};

  // ---- layer 1 K-loop (KT=12), depth-1 register pipeline ----
  {
    const u16* aw = w1b + (size_t)(w * 64 + l15) * 32 + quad * 8;
    const u16* bx = xin + (size_t)panel * 24576 + (size_t)l15 * 32 + quad * 8;
    short8 af[2][4], bf[2][4];
#pragma unroll
    for (int m = 0; m < 4; ++m)
      af[0][m] = *(const short8*)(aw + m * 512);
#pragma unroll
    for (int n = 0; n < 4; ++n)
      bf[0][n] = *(const short8*)(bx + n * 512);
#pragma unroll
    for (int kt = 0; kt < 12; ++kt) {
      int cur = kt & 1, nxt = cur ^ 1;
      if (kt < 11) {
#pragma unroll
        for (int m = 0; m < 4; ++m)
          af[nxt][m] = *(const short8*)(aw + (kt + 1) * 8192 + m * 512);
#pragma unroll
        for (int n = 0; n < 4; ++n)
          bf[nxt][n] = *(const short8*)(bx + (kt + 1) * 2048 + n * 512);
      }
#pragma unroll
      for (int m = 0; m < 4; ++m)
#pragma unroll
        for (int n = 0; n < 4; ++n)
          acc[m][n] = __builtin_amdgcn_mfma_f32_16x16x32_bf16(af[cur][m], bf[cur][n], acc[m][n], 0, 0, 0);
    }
  }

  // ---- epilogue 1: BN+ReLU -> bf16 -> LDS y1 tile (blocked, stride 40) ----
  {
    float al[4][4], bt[4][4];
#pragma unroll
    for (int m = 0; m < 4; ++m)
#pragma unroll
      for (int r = 0; r < 4; ++r) {
        int o = w * 64 + m * 16 + quad * 4 + r;
        al[m][r] = al1[o];
        bt[m][r] = bt1[o];
      }
#pragma unroll
    for (int m = 0; m < 4; ++m) {
      int kt2 = w * 2 + (m >> 1);
      int osub = (m & 1) * 16 + quad * 4;
#pragma unroll
      for (int n = 0; n < 4; ++n) {
        int col = n * 16 + l15;
        ushort4 pk;
        pk.x = f2b(fmaxf(fmaf(al[m][0], acc[m][n][0], bt[m][0]), 0.f));
        pk.y = f2b(fmaxf(fmaf(al[m][1], acc[m][n][1], bt[m][1]), 0.f));
        pk.z = f2b(fmaxf(fmaf(al[m][2], acc[m][n][2], bt[m][2]), 0.f));
        pk.w = f2b(fmaxf(fmaf(al[m][3], acc[m][n][3], bt[m][3]), 0.f));
        *(ushort4*)&y1t[(kt2 * 64 + col) * 40 + osub] = pk;
      }
    }
  }
  __syncthreads();

  // ---- layer 2 K-loop (KT=8): A global (depth-1 pipeline), B from LDS ----
#pragma unroll
  for (int m = 0; m < 4; ++m)
#pragma unroll
    for (int n = 0; n < 4; ++n)
      acc[m][n] = (f32x4){0.f, 0.f, 0.f, 0.f};
  {
    const u16* aw = w2b + (size_t)(w * 64 + l15) * 32 + quad * 8;
    short8 af[2][4];
#pragma unroll
    for (int m = 0; m < 4; ++m)
      af[0][m] = *(const short8*)(aw + m * 512);
#pragma unroll
    for (int kt = 0; kt < 8; ++kt) {
      int cur = kt & 1, nxt = cur ^ 1;
      if (kt < 7) {
#pragma unroll
        for (int m = 0; m < 4; ++m)
          af[nxt][m] = *(const short8*)(aw + (kt + 1) * 8192 + m * 512);
      }
      short8 bf[4];
#pragma unroll
      for (int n = 0; n < 4; ++n)
        bf[n] = *(const short8*)&y1t[(kt * 64 + n * 16 + l15) * 40 + quad * 8];
#pragma unroll
      for (int m = 0; m < 4; ++m)
#pragma unroll
        for (int n = 0; n < 4; ++n)
          acc[m][n] = __builtin_amdgcn_mfma_f32_16x16x32_bf16(af[cur][m], bf[n], acc[m][n], 0, 0, 0);
    }
  }

  // ---- epilogue 2: BN+ReLU -> f32 out [b][256][8192] ----
  {
    float al[4][4], bt[4][4];
#pragma unroll
    for (int m = 0; m < 4; ++m)
#pragma unroll
      for (int r = 0; r < 4; ++r) {
        int o = w * 64 + m * 16 + quad * 4 + r;
        al[m][r] = al2[o];
        bt[m][r] = bt2[o];
      }
    int bb = panel >> 7;
    int n1base = (panel & 127) * 64;
#pragma unroll
    for (int m = 0; m < 4; ++m)
#pragma unroll
      for (int n = 0; n < 4; ++n) {
        int col = n * 16 + l15;
#pragma unroll
        for (int r = 0; r < 4; ++r) {
          int o = w * 64 + m * 16 + quad * 4 + r;
          float vv = fmaxf(fmaf(al[m][r], acc[m][n][r], bt[m][r]), 0.f);
          fout[(size_t)(bb * 256 + o) * 8192 + n1base + col] = vv;
        }
      }
  }
}

// ---------------------------------------------------------------------------
// ws layout (bytes):
//   [0,          50331648)  xb   bf16 [1024 panels][12][64][32]   48 MB
//   [50331648,   58720256)  f2t  bf16 [8][2048][256]               8 MB
//   [83886080,   84082688)  w1b  bf16 blocked
//   [84082688,   84213760)  w2b  bf16 blocked
//   [84213760,   84217856)  al1/bt1/al2/bt2 f32
// ---------------------------------------------------------------------------
extern "C" void kernel_launch(void* const* d_in, const int* in_sizes, int n_in,
                              void* d_out, int out_size, void* d_ws, size_t ws_size,
                              hipStream_t stream) {
  const float* xyz1 = (const float*)d_in[0];
  const float* xyz2 = (const float*)d_in[1];
  const float* f1   = (const float*)d_in[2];
  const float* f2   = (const float*)d_in[3];
  const float* w1   = (const float*)d_in[4];
  const float* b1   = (const float*)d_in[5];
  const float* g1   = (const float*)d_in[6];
  const float* be1  = (const float*)d_in[7];
  const float* m1   = (const float*)d_in[8];
  const float* v1   = (const float*)d_in[9];
  const float* w2   = (const float*)d_in[10];
  const float* b2   = (const float*)d_in[11];
  const float* g2   = (const float*)d_in[12];
  const float* be2  = (const float*)d_in[13];
  const float* m2   = (const float*)d_in[14];
  const float* v2   = (const float*)d_in[15];

  char* ws = (char*)d_ws;
  u16* xb   = (u16*)(ws);
  u16* f2t  = (u16*)(ws + 50331648);
  u16* w1b  = (u16*)(ws + 83886080);
  u16* w2b  = (u16*)(ws + 84082688);
  float* al1 = (float*)(ws + 84213760);
  float* bt1 = (float*)(ws + 84214784);
  float* al2 = (float*)(ws + 84215808);
  float* bt2 = (float*)(ws + 84216832);
  float* out = (float*)d_out;

  prep_transpose_kernel<<<4738, 256, 0, stream>>>(
      f2, f2t, w1, b1, g1, be1, m1, v1, w2, b2, g2, be2, m2, v2,
      w1b, w2b, al1, bt1, al2, bt2);
  knn_interp_kernel<<<512, 512, 0, stream>>>(xyz1, xyz2, f1, f2t, xb);
  gemm_fused_kernel<<<1024, 256, 0, stream>>>(xb, w1b, w2b, al1, bt1, al2, bt2, out);
}

// Round 10
// 227.246 us; speedup vs baseline: 1.3909x; 1.0373x over previous
//
#include <hip/hip_runtime.h>
#include <hip/hip_bf16.h>

typedef unsigned short u16;
typedef __attribute__((ext_vector_type(4))) float f32x4;
typedef __attribute__((ext_vector_type(8))) short short8;

#define BN_EPS 1e-5f

__device__ __forceinline__ u16 f2b(float x) {
  union { float f; unsigned int u; } v; v.f = x;
  unsigned int r = (v.u + 0x7FFFu + ((v.u >> 16) & 1u)) >> 16;
  return (u16)r;
}
__device__ __forceinline__ float b2f(u16 u) {
  union { unsigned int u; float f; } v; v.u = ((unsigned int)u) << 16;
  return v.f;
}
__device__ __forceinline__ float asf(unsigned u) {
  union { unsigned u; float f; } v; v.u = u; return v.f;
}

// ---------------------------------------------------------------------------
// prep + transpose fused (round-2/5 proven version).
// ---------------------------------------------------------------------------
__global__ void prep_transpose_kernel(
    const float* __restrict__ f2, u16* __restrict__ f2t,
    const float* __restrict__ w1, const float* __restrict__ b1,
    const float* __restrict__ g1, const float* __restrict__ be1,
    const float* __restrict__ m1, const float* __restrict__ v1,
    const float* __restrict__ w2, const float* __restrict__ b2,
    const float* __restrict__ g2, const float* __restrict__ be2,
    const float* __restrict__ m2, const float* __restrict__ v2,
    u16* __restrict__ w1b, u16* __restrict__ w2b,
    float* __restrict__ al1, float* __restrict__ bt1,
    float* __restrict__ al2, float* __restrict__ bt2) {
  __shared__ float tile[32][33];
  int t = threadIdx.x;
  int blk = blockIdx.x;
  if (blk < 4096) {
    int tx = t & 31, ty = t >> 5;        // ty in [0,8)
    int b = (blk >> 9) & 7;
    int n2t = (blk & 63) * 32, ct = ((blk >> 6) & 7) * 32;
#pragma unroll
    for (int i = 0; i < 4; ++i) {
      int c = ct + ty + i * 8;
      tile[ty + i * 8][tx] = f2[((size_t)b * 256 + c) * 2048 + n2t + tx];
    }
    __syncthreads();
#pragma unroll
    for (int i = 0; i < 4; ++i) {
      int n2 = n2t + ty + i * 8;
      f2t[((size_t)b * 2048 + n2) * 256 + ct + tx] = f2b(tile[tx][ty + i * 8]);
    }
  } else if (blk < 4480) {               // w1: 256x384
    int id = (blk - 4096) * 256 + t;
    unsigned o = (unsigned)id / 384u;
    unsigned c = (unsigned)id % 384u;
    w1b[(c >> 5) * 8192 + o * 32 + (c & 31)] = f2b(w1[id]);
  } else if (blk < 4736) {               // w2: 256x256
    int j = (blk - 4480) * 256 + t;
    unsigned o = (unsigned)j >> 8;
    unsigned c = (unsigned)j & 255u;
    w2b[(c >> 5) * 8192 + o * 32 + (c & 31)] = f2b(w2[j]);
  } else if (blk == 4736) {
    float a = g1[t] / sqrtf(v1[t] + BN_EPS);
    al1[t] = a;
    bt1[t] = (b1[t] - m1[t]) * a + be1[t];
  } else {
    float a = g2[t] / sqrtf(v2[t] + BN_EPS);
    al2[t] = a;
    bt2[t] = (b2[t] - m2[t]) * a + be2[t];
  }
}

// ---------------------------------------------------------------------------
// knn + interp + skip-copy — R5 structure (4 waves/block, 1 query/lane,
// 512-candidate slices, gated insertion network) with SoA candidate store:
// px/py/pz only (24 KB, no |c|^2 column) read as 3 ds_read_b128 per FOUR
// candidates -> scan LDS-pipe reads x0.75 (the measured R5 floor).
// |c|^2 is recomputed per lane with the character-identical expression the
// staging used -> sq bits unchanged -> selection identical. LDS ~35 KB.
// ---------------------------------------------------------------------------
__global__ __launch_bounds__(256) void knn_interp_kernel(
    const float* __restrict__ xyz1, const float* __restrict__ xyz2,
    const float* __restrict__ f1, const u16* __restrict__ f2t,
    u16* __restrict__ xb) {
  union Lds {
    struct {
      float px[2048], py[2048], pz[2048];   // 24576 B
      float md[256 * 3];                    //  3072 B
      u16 mi[256 * 3];                      //  1536 B
    } a;
    float f1t[128 * 65];                    // 33280 B
  };
  __shared__ Lds lds;
  __shared__ float wts[64 * 3];
  __shared__ int idxs[64 * 3];           // premultiplied by 256

  int t = threadIdx.x;
  int b = blockIdx.x >> 7;
  int n1_0 = (blockIdx.x & 127) * 64;
  int panel = blockIdx.x;                // = b*128 + tile

  // phase 0: stage candidates (x,y,z) SoA
  const float* x2 = xyz2 + b * 3 * 2048;
  for (int j = t; j < 2048; j += 256) {
    lds.a.px[j] = x2[j];
    lds.a.py[j] = x2[2048 + j];
    lds.a.pz[j] = x2[4096 + j];
  }
  __syncthreads();

  const float* x1 = xyz1 + b * 3 * 8192;

  // phase 1: sliced top-3; lane = query, wave = slice (broadcast LDS reads)
  {
    int p = t & 63, s = t >> 6;
    int n1 = n1_0 + p;
    float bx = x1[n1], by = x1[8192 + n1], bz = x1[16384 + n1];
    float nx = -2.f * bx, ny = -2.f * by, nz = -2.f * bz;
    // comparator value: sq' = |c|^2 - 2 q.c  (biased by -|q|^2, rank-equal)
    float d0 = 3.4e38f, d1 = 3.4e38f, d2 = 3.4e38f;
    int i0 = 0, i1 = 0, i2 = 0;
    int jb = s * 512;

#define KNN_UPD(cx_, cy_, cz_, jv)                                           \
    {                                                                        \
      float cw_ = (cx_ * cx_ + cy_ * cy_) + cz_ * cz_;                       \
      float sq = fmaf(nx, cx_, fmaf(ny, cy_, fmaf(nz, cz_, cw_)));           \
      if (__any(sq < d2)) {                                                  \
        bool c0 = sq < d0, c1 = sq < d1, c2 = sq < d2;                       \
        i2 = c1 ? i1 : (c2 ? (jv) : i2);                                     \
        i1 = c0 ? i0 : (c1 ? (jv) : i1);                                     \
        i0 = c0 ? (jv) : i0;                                                 \
        d2 = __builtin_amdgcn_fmed3f(sq, d1, d2);                            \
        d1 = __builtin_amdgcn_fmed3f(sq, d0, d1);                            \
        d0 = fminf(sq, d0);                                                  \
      }                                                                      \
    }

    for (int jj = 0; jj < 512; jj += 4) {
      float4 vx = *(const float4*)&lds.a.px[jb + jj];
      float4 vy = *(const float4*)&lds.a.py[jb + jj];
      float4 vz = *(const float4*)&lds.a.pz[jb + jj];
      KNN_UPD(vx.x, vy.x, vz.x, jb + jj + 0);
      KNN_UPD(vx.y, vy.y, vz.y, jb + jj + 1);
      KNN_UPD(vx.z, vy.z, vz.z, jb + jj + 2);
      KNN_UPD(vx.w, vy.w, vz.w, jb + jj + 3);
    }
#undef KNN_UPD
    lds.a.md[t * 3 + 0] = d0; lds.a.md[t * 3 + 1] = d1; lds.a.md[t * 3 + 2] = d2;
    lds.a.mi[t * 3 + 0] = (u16)i0; lds.a.mi[t * 3 + 1] = (u16)i1; lds.a.mi[t * 3 + 2] = (u16)i2;
  }
  __syncthreads();
  if (t < 64) {
    // merge slices s=0..3 in ascending-index order (preserves tie-break)
    float d0 = 3.4e38f, d1 = 3.4e38f, d2 = 3.4e38f;
    int i0 = 0, i1 = 0, i2 = 0;
#pragma unroll
    for (int s = 0; s < 4; ++s) {
#pragma unroll
      for (int k = 0; k < 3; ++k) {
        float d = lds.a.md[(s * 64 + t) * 3 + k];
        int i = (int)lds.a.mi[(s * 64 + t) * 3 + k];
        bool c0 = d < d0, c1 = d < d1, c2 = d < d2;
        i2 = c1 ? i1 : (c2 ? i : i2);
        i1 = c0 ? i0 : (c1 ? i : i1);
        i0 = c0 ? i : i0;
        d2 = c1 ? d1 : (c2 ? d : d2);
        d1 = c0 ? d0 : (c1 ? d : d1);
        d0 = c0 ? d : d0;
      }
    }
    // un-bias: recompute |q|^2 for this query (3 L1-hot loads, 64 threads)
    int n1 = n1_0 + t;
    float bx = x1[n1], by = x1[8192 + n1], bz = x1[16384 + n1];
    float nn = (bx * bx + by * by) + bz * bz;
    float e0 = fmaxf(d0 + nn, 1e-10f), e1 = fmaxf(d1 + nn, 1e-10f), e2 = fmaxf(d2 + nn, 1e-10f);
    float w0 = 1.0f / e0, w1 = 1.0f / e1, w2 = 1.0f / e2;
    float sm = (w0 + w1) + w2;
    wts[t * 3 + 0] = w0 / sm; wts[t * 3 + 1] = w1 / sm; wts[t * 3 + 2] = w2 / sm;
    idxs[t * 3 + 0] = i0 * 256; idxs[t * 3 + 1] = i1 * 256; idxs[t * 3 + 2] = i2 * 256;
  }
  __syncthreads();

  // phase 2: interp 256 channels as 64 channel-quads x 4 query groups
  {
    const u16* f2tb = f2t + (size_t)b * 2048 * 256;
    int tc = t & 63;                     // channel quad: channels 4tc..4tc+3
    int qg = t >> 6;                     // query group (uniform per wave)
    int ce = (4 * tc) & 31;              // channel offset within 32-block
    size_t xbase = (size_t)panel * 24576 + (size_t)(tc >> 3) * 2048 + ce;
#pragma unroll 4
    for (int p2 = 0; p2 < 16; ++p2) {
      int p = p2 * 4 + qg;
      int j0 = idxs[p * 3 + 0], j1 = idxs[p * 3 + 1], j2 = idxs[p * 3 + 2];
      float w0 = wts[p * 3 + 0], w1 = wts[p * 3 + 1], w2 = wts[p * 3 + 2];
      uint2 a0 = *(const uint2*)&f2tb[j0 + 4 * tc];
      uint2 a1 = *(const uint2*)&f2tb[j1 + 4 * tc];
      uint2 a2 = *(const uint2*)&f2tb[j2 + 4 * tc];
      float v0 = (w0 * asf(a0.x << 16) + w1 * asf(a1.x << 16)) + w2 * asf(a2.x << 16);
      float v1 = (w0 * asf(a0.x & 0xffff0000u) + w1 * asf(a1.x & 0xffff0000u))
                 + w2 * asf(a2.x & 0xffff0000u);
      float v2 = (w0 * asf(a0.y << 16) + w1 * asf(a1.y << 16)) + w2 * asf(a2.y << 16);
      float v3 = (w0 * asf(a0.y & 0xffff0000u) + w1 * asf(a1.y & 0xffff0000u))
                 + w2 * asf(a2.y & 0xffff0000u);
      uint2 pk;
      pk.x = (unsigned)f2b(v0) | ((unsigned)f2b(v1) << 16);
      pk.y = (unsigned)f2b(v2) | ((unsigned)f2b(v3) << 16);
      *(uint2*)&xb[xbase + (size_t)p * 32] = pk;
    }
  }
  __syncthreads();   // before aliasing lds.a with lds.f1t

  // phase 3: skip features (channels 256..383) via LDS transpose
  {
    const float* f1b = f1 + (size_t)b * 128 * 8192 + n1_0;
    for (int it = 0; it < 32; ++it) {
      int c = it * 4 + (t >> 6);
      int n = t & 63;
      lds.f1t[c * 65 + n] = f1b[(size_t)c * 8192 + n];
    }
    __syncthreads();
    for (int it = 0; it < 32; ++it) {
      int v = it * 256 + t;
      int c = v & 127, p = v >> 7;
      float val = lds.f1t[c * 65 + p];
      xb[(size_t)panel * 24576 + (size_t)(8 + (c >> 5)) * 2048 + p * 32 + (c & 31)] = f2b(val);
    }
  }
}

// ---------------------------------------------------------------------------
// FUSED 2-layer GEMM. Layer-1 B-operand now runs a DEPTH-2 register pipeline
// (bf[3][4], loads issued 2 kt ahead): xb is stream-once from L3 (~600 cy);
// depth-1's one-MFMA-block slack (~240 cy) under-covered it. Full unroll
// keeps all indices compile-time (no scratch). A-side (L2-hot weights)
// stays depth-1. Layer 2 unchanged.
// ---------------------------------------------------------------------------
__global__ __launch_bounds__(256) void gemm_fused_kernel(
    const u16* __restrict__ xin, const u16* __restrict__ w1b,
    const u16* __restrict__ w2b,
    const float* __restrict__ al1, const float* __restrict__ bt1,
    const float* __restrict__ al2, const float* __restrict__ bt2,
    float* __restrict__ fout) {
  __shared__ u16 y1t[8 * 64 * 40];       // 40960 B
  int t = threadIdx.x;
  int panel = blockIdx.x;
  int w = t >> 6, lane = t & 63, l15 = lane & 15, quad = lane >> 4;

  f32x4 acc[4][4];
#pragma unroll
  for (int m = 0; m < 4; ++m)
#pragma unroll
    for (int n = 0; n < 4; ++n)
      acc[m][n] = (f32x4){0.f, 0.f, 0.f, 0.f};

  // ---- layer 1 K-loop (KT=12): A depth-1, B depth-2 register pipeline ----
  {
    const u16* aw = w1b + (size_t)(w * 64 + l15) * 32 + quad * 8;
    const u16* bx = xin + (size_t)panel * 24576 + (size_t)l15 * 32 + quad * 8;
    short8 af[2][4], bf[3][4];
#pragma unroll
    for (int m = 0; m < 4; ++m)
      af[0][m] = *(const short8*)(aw + m * 512);
#pragma unroll
    for (int n = 0; n < 4; ++n)
      bf[0][n] = *(const short8*)(bx + n * 512);
#pragma unroll
    for (int n = 0; n < 4; ++n)
      bf[1][n] = *(const short8*)(bx + 2048 + n * 512);
#pragma unroll
    for (int kt = 0; kt < 12; ++kt) {
      int cur = kt & 1, nxt = cur ^ 1;
      if (kt < 11) {
#pragma unroll
        for (int m = 0; m < 4; ++m)
          af[nxt][m] = *(const short8*)(aw + (kt + 1) * 8192 + m * 512);
      }
      if (kt < 10) {
#pragma unroll
        for (int n = 0; n < 4; ++n)
          bf[(kt + 2) % 3][n] = *(const short8*)(bx + (kt + 2) * 2048 + n * 512);
      }
#pragma unroll
      for (int m = 0; m < 4; ++m)
#pragma unroll
        for (int n = 0; n < 4; ++n)
          acc[m][n] = __builtin_amdgcn_mfma_f32_16x16x32_bf16(af[cur][m], bf[kt % 3][n], acc[m][n], 0, 0, 0);
    }
  }

  // ---- epilogue 1: BN+ReLU -> bf16 -> LDS y1 tile (blocked, stride 40) ----
  {
    float al[4][4], bt[4][4];
#pragma unroll
    for (int m = 0; m < 4; ++m)
#pragma unroll
      for (int r = 0; r < 4; ++r) {
        int o = w * 64 + m * 16 + quad * 4 + r;
        al[m][r] = al1[o];
        bt[m][r] = bt1[o];
      }
#pragma unroll
    for (int m = 0; m < 4; ++m) {
      int kt2 = w * 2 + (m >> 1);
      int osub = (m & 1) * 16 + quad * 4;
#pragma unroll
      for (int n = 0; n < 4; ++n) {
        int col = n * 16 + l15;
        ushort4 pk;
        pk.x = f2b(fmaxf(fmaf(al[m][0], acc[m][n][0], bt[m][0]), 0.f));
        pk.y = f2b(fmaxf(fmaf(al[m][1], acc[m][n][1], bt[m][1]), 0.f));
        pk.z = f2b(fmaxf(fmaf(al[m][2], acc[m][n][2], bt[m][2]), 0.f));
        pk.w = f2b(fmaxf(fmaf(al[m][3], acc[m][n][3], bt[m][3]), 0.f));
        *(ushort4*)&y1t[(kt2 * 64 + col) * 40 + osub] = pk;
      }
    }
  }
  __syncthreads();

  // ---- layer 2 K-loop (KT=8): A global (depth-1 pipeline), B from LDS ----
#pragma unroll
  for (int m = 0; m < 4; ++m)
#pragma unroll
    for (int n = 0; n < 4; ++n)
      acc[m][n] = (f32x4){0.f, 0.f, 0.f, 0.f};
  {
    const u16* aw = w2b + (size_t)(w * 64 + l15) * 32 + quad * 8;
    short8 af[2][4];
#pragma unroll
    for (int m = 0; m < 4; ++m)
      af[0][m] = *(const short8*)(aw + m * 512);
#pragma unroll
    for (int kt = 0; kt < 8; ++kt) {
      int cur = kt & 1, nxt = cur ^ 1;
      if (kt < 7) {
#pragma unroll
        for (int m = 0; m < 4; ++m)
          af[nxt][m] = *(const short8*)(aw + (kt + 1) * 8192 + m * 512);
      }
      short8 bf[4];
#pragma unroll
      for (int n = 0; n < 4; ++n)
        bf[n] = *(const short8*)&y1t[(kt * 64 + n * 16 + l15) * 40 + quad * 8];
#pragma unroll
      for (int m = 0; m < 4; ++m)
#pragma unroll
        for (int n = 0; n < 4; ++n)
          acc[m][n] = __builtin_amdgcn_mfma_f32_16x16x32_bf16(af[cur][m], bf[n], acc[m][n], 0, 0, 0);
    }
  }

  // ---- epilogue 2: BN+ReLU -> f32 out [b][256][8192] ----
  {
    float al[4][4], bt[4][4];
#pragma unroll
    for (int m = 0; m < 4; ++m)
#pragma unroll
      for (int r = 0; r < 4; ++r) {
        int o = w * 64 + m * 16 + quad * 4 + r;
        al[m][r] = al2[o];
        bt[m][r] = bt2[o];
      }
    int bb = panel >> 7;
    int n1base = (panel & 127) * 64;
#pragma unroll
    for (int m = 0; m < 4; ++m)
#pragma unroll
      for (int n = 0; n < 4; ++n) {
        int col = n * 16 + l15;
#pragma unroll
        for (int r = 0; r < 4; ++r) {
          int o = w * 64 + m * 16 + quad * 4 + r;
          float vv = fmaxf(fmaf(al[m][r], acc[m][n][r], bt[m][r]), 0.f);
          fout[(size_t)(bb * 256 + o) * 8192 + n1base + col] = vv;
        }
      }
  }
}

// ---------------------------------------------------------------------------
// ws layout (bytes):
//   [0,          50331648)  xb   bf16 [1024 panels][12][64][32]   48 MB
//   [50331648,   58720256)  f2t  bf16 [8][2048][256]               8 MB
//   [83886080,   84082688)  w1b  bf16 blocked
//   [84082688,   84213760)  w2b  bf16 blocked
//   [84213760,   84217856)  al1/bt1/al2/bt2 f32
// ---------------------------------------------------------------------------
extern "C" void kernel_launch(void* const* d_in, const int* in_sizes, int n_in,
                              void* d_out, int out_size, void* d_ws, size_t ws_size,
                              hipStream_t stream) {
  const float* xyz1 = (const float*)d_in[0];
  const float* xyz2 = (const float*)d_in[1];
  const float* f1   = (const float*)d_in[2];
  const float* f2   = (const float*)d_in[3];
  const float* w1   = (const float*)d_in[4];
  const float* b1   = (const float*)d_in[5];
  const float* g1   = (const float*)d_in[6];
  const float* be1  = (const float*)d_in[7];
  const float* m1   = (const float*)d_in[8];
  const float* v1   = (const float*)d_in[9];
  const float* w2   = (const float*)d_in[10];
  const float* b2   = (const float*)d_in[11];
  const float* g2   = (const float*)d_in[12];
  const float* be2  = (const float*)d_in[13];
  const float* m2   = (const float*)d_in[14];
  const float* v2   = (const float*)d_in[15];

  char* ws = (char*)d_ws;
  u16* xb   = (u16*)(ws);
  u16* f2t  = (u16*)(ws + 50331648);
  u16* w1b  = (u16*)(ws + 83886080);
  u16* w2b  = (u16*)(ws + 84082688);
  float* al1 = (float*)(ws + 84213760);
  float* bt1 = (float*)(ws + 84214784);
  float* al2 = (float*)(ws + 84215808);
  float* bt2 = (float*)(ws + 84216832);
  float* out = (float*)d_out;

  prep_transpose_kernel<<<4738, 256, 0, stream>>>(
      f2, f2t, w1, b1, g1, be1, m1, v1, w2, b2, g2, be2, m2, v2,
      w1b, w2b, al1, bt1, al2, bt2);
  knn_interp_kernel<<<1024, 256, 0, stream>>>(xyz1, xyz2, f1, f2t, xb);
  gemm_fused_kernel<<<1024, 256, 0, stream>>>(xb, w1b, w2b, al1, bt1, al2, bt2, out);
}

// Round 11
// 215.034 us; speedup vs baseline: 1.4699x; 1.0568x over previous
//
#include <hip/hip_runtime.h>
#include <hip/hip_bf16.h>

typedef unsigned short u16;
typedef __attribute__((ext_vector_type(4))) float f32x4;
typedef __attribute__((ext_vector_type(8))) short short8;

#define BN_EPS 1e-5f

__device__ __forceinline__ u16 f2b(float x) {
  union { float f; unsigned int u; } v; v.f = x;
  unsigned int r = (v.u + 0x7FFFu + ((v.u >> 16) & 1u)) >> 16;
  return (u16)r;
}
__device__ __forceinline__ float b2f(u16 u) {
  union { unsigned int u; float f; } v; v.u = ((unsigned int)u) << 16;
  return v.f;
}
__device__ __forceinline__ float asf(unsigned u) {
  union { unsigned u; float f; } v; v.u = u; return v.f;
}

// ---------------------------------------------------------------------------
// prep + transpose fused (round-2/5 proven version).
// ---------------------------------------------------------------------------
__global__ void prep_transpose_kernel(
    const float* __restrict__ f2, u16* __restrict__ f2t,
    const float* __restrict__ w1, const float* __restrict__ b1,
    const float* __restrict__ g1, const float* __restrict__ be1,
    const float* __restrict__ m1, const float* __restrict__ v1,
    const float* __restrict__ w2, const float* __restrict__ b2,
    const float* __restrict__ g2, const float* __restrict__ be2,
    const float* __restrict__ m2, const float* __restrict__ v2,
    u16* __restrict__ w1b, u16* __restrict__ w2b,
    float* __restrict__ al1, float* __restrict__ bt1,
    float* __restrict__ al2, float* __restrict__ bt2) {
  __shared__ float tile[32][33];
  int t = threadIdx.x;
  int blk = blockIdx.x;
  if (blk < 4096) {
    int tx = t & 31, ty = t >> 5;        // ty in [0,8)
    int b = (blk >> 9) & 7;
    int n2t = (blk & 63) * 32, ct = ((blk >> 6) & 7) * 32;
#pragma unroll
    for (int i = 0; i < 4; ++i) {
      int c = ct + ty + i * 8;
      tile[ty + i * 8][tx] = f2[((size_t)b * 256 + c) * 2048 + n2t + tx];
    }
    __syncthreads();
#pragma unroll
    for (int i = 0; i < 4; ++i) {
      int n2 = n2t + ty + i * 8;
      f2t[((size_t)b * 2048 + n2) * 256 + ct + tx] = f2b(tile[tx][ty + i * 8]);
    }
  } else if (blk < 4480) {               // w1: 256x384
    int id = (blk - 4096) * 256 + t;
    unsigned o = (unsigned)id / 384u;
    unsigned c = (unsigned)id % 384u;
    w1b[(c >> 5) * 8192 + o * 32 + (c & 31)] = f2b(w1[id]);
  } else if (blk < 4736) {               // w2: 256x256
    int j = (blk - 4480) * 256 + t;
    unsigned o = (unsigned)j >> 8;
    unsigned c = (unsigned)j & 255u;
    w2b[(c >> 5) * 8192 + o * 32 + (c & 31)] = f2b(w2[j]);
  } else if (blk == 4736) {
    float a = g1[t] / sqrtf(v1[t] + BN_EPS);
    al1[t] = a;
    bt1[t] = (b1[t] - m1[t]) * a + be1[t];
  } else {
    float a = g2[t] / sqrtf(v2[t] + BN_EPS);
    al2[t] = a;
    bt2[t] = (b2[t] - m2[t]) * a + be2[t];
  }
}

// ---------------------------------------------------------------------------
// knn + interp + skip-copy — R5 verbatim (best measured: 71.2 us) except the
// scan unroll widened 4 -> 8 (8 ds_read_b128 batched ahead of 8 gated update
// blocks: deeper lgkm overlap, zero semantic change).
// ---------------------------------------------------------------------------
__global__ __launch_bounds__(256) void knn_interp_kernel(
    const float* __restrict__ xyz1, const float* __restrict__ xyz2,
    const float* __restrict__ f1, const u16* __restrict__ f2t,
    u16* __restrict__ xb) {
  union Lds {
    struct { float4 pts[2048]; float md[256 * 3]; u16 mi[256 * 3]; } a;
    float f1t[128 * 65];
  };
  __shared__ Lds lds;
  __shared__ float wts[64 * 3];
  __shared__ int idxs[64 * 3];           // premultiplied by 256

  int t = threadIdx.x;
  int b = blockIdx.x >> 7;
  int n1_0 = (blockIdx.x & 127) * 64;
  int panel = blockIdx.x;                // = b*128 + tile

  // phase 0: stage candidates (x,y,z,|x|^2)
  const float* x2 = xyz2 + b * 3 * 2048;
  for (int j = t; j < 2048; j += 256) {
    float cx = x2[j], cy = x2[2048 + j], cz = x2[4096 + j];
    float nsq = (cx * cx + cy * cy) + cz * cz;
    lds.a.pts[j] = make_float4(cx, cy, cz, nsq);
  }
  __syncthreads();

  const float* x1 = xyz1 + b * 3 * 8192;

  // phase 1: sliced top-3; lane = query, wave = slice (broadcast LDS reads)
  {
    int p = t & 63, s = t >> 6;
    int n1 = n1_0 + p;
    float bx = x1[n1], by = x1[8192 + n1], bz = x1[16384 + n1];
    float nx = -2.f * bx, ny = -2.f * by, nz = -2.f * bz;
    // comparator value: sq' = |c|^2 - 2 q.c  (biased by -|q|^2, rank-equal)
    float d0 = 3.4e38f, d1 = 3.4e38f, d2 = 3.4e38f;
    int i0 = 0, i1 = 0, i2 = 0;
    int jb = s * 512;

#define KNN_UPD(cv, jv)                                                      \
    {                                                                        \
      float sq = fmaf(nx, (cv).x, fmaf(ny, (cv).y, fmaf(nz, (cv).z, (cv).w))); \
      if (__any(sq < d2)) {                                                  \
        bool c0 = sq < d0, c1 = sq < d1, c2 = sq < d2;                       \
        i2 = c1 ? i1 : (c2 ? (jv) : i2);                                     \
        i1 = c0 ? i0 : (c1 ? (jv) : i1);                                     \
        i0 = c0 ? (jv) : i0;                                                 \
        d2 = __builtin_amdgcn_fmed3f(sq, d1, d2);                            \
        d1 = __builtin_amdgcn_fmed3f(sq, d0, d1);                            \
        d0 = fminf(sq, d0);                                                  \
      }                                                                      \
    }

    for (int jj = 0; jj < 512; jj += 8) {
      float4 c0v = lds.a.pts[jb + jj + 0];
      float4 c1v = lds.a.pts[jb + jj + 1];
      float4 c2v = lds.a.pts[jb + jj + 2];
      float4 c3v = lds.a.pts[jb + jj + 3];
      float4 c4v = lds.a.pts[jb + jj + 4];
      float4 c5v = lds.a.pts[jb + jj + 5];
      float4 c6v = lds.a.pts[jb + jj + 6];
      float4 c7v = lds.a.pts[jb + jj + 7];
      KNN_UPD(c0v, jb + jj + 0);
      KNN_UPD(c1v, jb + jj + 1);
      KNN_UPD(c2v, jb + jj + 2);
      KNN_UPD(c3v, jb + jj + 3);
      KNN_UPD(c4v, jb + jj + 4);
      KNN_UPD(c5v, jb + jj + 5);
      KNN_UPD(c6v, jb + jj + 6);
      KNN_UPD(c7v, jb + jj + 7);
    }
#undef KNN_UPD
    lds.a.md[t * 3 + 0] = d0; lds.a.md[t * 3 + 1] = d1; lds.a.md[t * 3 + 2] = d2;
    lds.a.mi[t * 3 + 0] = (u16)i0; lds.a.mi[t * 3 + 1] = (u16)i1; lds.a.mi[t * 3 + 2] = (u16)i2;
  }
  __syncthreads();
  if (t < 64) {
    // merge slices s=0..3 in ascending-index order (preserves tie-break)
    float d0 = 3.4e38f, d1 = 3.4e38f, d2 = 3.4e38f;
    int i0 = 0, i1 = 0, i2 = 0;
#pragma unroll
    for (int s = 0; s < 4; ++s) {
#pragma unroll
      for (int k = 0; k < 3; ++k) {
        float d = lds.a.md[(s * 64 + t) * 3 + k];
        int i = (int)lds.a.mi[(s * 64 + t) * 3 + k];
        bool c0 = d < d0, c1 = d < d1, c2 = d < d2;
        i2 = c1 ? i1 : (c2 ? i : i2);
        i1 = c0 ? i0 : (c1 ? i : i1);
        i0 = c0 ? i : i0;
        d2 = c1 ? d1 : (c2 ? d : d2);
        d1 = c0 ? d0 : (c1 ? d : d1);
        d0 = c0 ? d : d0;
      }
    }
    // un-bias: recompute |q|^2 for this query (3 L1-hot loads, 64 threads)
    int n1 = n1_0 + t;
    float bx = x1[n1], by = x1[8192 + n1], bz = x1[16384 + n1];
    float nn = (bx * bx + by * by) + bz * bz;
    float e0 = fmaxf(d0 + nn, 1e-10f), e1 = fmaxf(d1 + nn, 1e-10f), e2 = fmaxf(d2 + nn, 1e-10f);
    float w0 = 1.0f / e0, w1 = 1.0f / e1, w2 = 1.0f / e2;
    float sm = (w0 + w1) + w2;
    wts[t * 3 + 0] = w0 / sm; wts[t * 3 + 1] = w1 / sm; wts[t * 3 + 2] = w2 / sm;
    idxs[t * 3 + 0] = i0 * 256; idxs[t * 3 + 1] = i1 * 256; idxs[t * 3 + 2] = i2 * 256;
  }
  __syncthreads();

  // phase 2: interp 256 channels as 64 channel-quads x 4 query groups
  {
    const u16* f2tb = f2t + (size_t)b * 2048 * 256;
    int tc = t & 63;                     // channel quad: channels 4tc..4tc+3
    int qg = t >> 6;                     // query group (uniform per wave)
    int ce = (4 * tc) & 31;              // channel offset within 32-block
    size_t xbase = (size_t)panel * 24576 + (size_t)(tc >> 3) * 2048 + ce;
#pragma unroll 4
    for (int p2 = 0; p2 < 16; ++p2) {
      int p = p2 * 4 + qg;
      int j0 = idxs[p * 3 + 0], j1 = idxs[p * 3 + 1], j2 = idxs[p * 3 + 2];
      float w0 = wts[p * 3 + 0], w1 = wts[p * 3 + 1], w2 = wts[p * 3 + 2];
      uint2 a0 = *(const uint2*)&f2tb[j0 + 4 * tc];
      uint2 a1 = *(const uint2*)&f2tb[j1 + 4 * tc];
      uint2 a2 = *(const uint2*)&f2tb[j2 + 4 * tc];
      float v0 = (w0 * asf(a0.x << 16) + w1 * asf(a1.x << 16)) + w2 * asf(a2.x << 16);
      float v1 = (w0 * asf(a0.x & 0xffff0000u) + w1 * asf(a1.x & 0xffff0000u))
                 + w2 * asf(a2.x & 0xffff0000u);
      float v2 = (w0 * asf(a0.y << 16) + w1 * asf(a1.y << 16)) + w2 * asf(a2.y << 16);
      float v3 = (w0 * asf(a0.y & 0xffff0000u) + w1 * asf(a1.y & 0xffff0000u))
                 + w2 * asf(a2.y & 0xffff0000u);
      uint2 pk;
      pk.x = (unsigned)f2b(v0) | ((unsigned)f2b(v1) << 16);
      pk.y = (unsigned)f2b(v2) | ((unsigned)f2b(v3) << 16);
      *(uint2*)&xb[xbase + (size_t)p * 32] = pk;
    }
  }
  __syncthreads();   // before aliasing lds.a with lds.f1t

  // phase 3: skip features (channels 256..383) via LDS transpose
  {
    const float* f1b = f1 + (size_t)b * 128 * 8192 + n1_0;
    for (int it = 0; it < 32; ++it) {
      int c = it * 4 + (t >> 6);
      int n = t & 63;
      lds.f1t[c * 65 + n] = f1b[(size_t)c * 8192 + n];
    }
    __syncthreads();
    for (int it = 0; it < 32; ++it) {
      int v = it * 256 + t;
      int c = v & 127, p = v >> 7;
      float val = lds.f1t[c * 65 + p];
      xb[(size_t)panel * 24576 + (size_t)(8 + (c >> 5)) * 2048 + p * 32 + (c & 31)] = f2b(val);
    }
  }
}

// ---------------------------------------------------------------------------
// FUSED 2-layer GEMM. Layer-1 B depth-2 register pipeline (R10: isolated
// ~+2.5 us vs depth-1 — xb is stream-once from L2/L3, depth-1 under-covered
// the latency). A-side depth-1 (L2-hot weights). Layer 2 unchanged.
// ---------------------------------------------------------------------------
__global__ __launch_bounds__(256) void gemm_fused_kernel(
    const u16* __restrict__ xin, const u16* __restrict__ w1b,
    const u16* __restrict__ w2b,
    const float* __restrict__ al1, const float* __restrict__ bt1,
    const float* __restrict__ al2, const float* __restrict__ bt2,
    float* __restrict__ fout) {
  __shared__ u16 y1t[8 * 64 * 40];       // 40960 B
  int t = threadIdx.x;
  int panel = blockIdx.x;
  int w = t >> 6, lane = t & 63, l15 = lane & 15, quad = lane >> 4;

  f32x4 acc[4][4];
#pragma unroll
  for (int m = 0; m < 4; ++m)
#pragma unroll
    for (int n = 0; n < 4; ++n)
      acc[m][n] = (f32x4){0.f, 0.f, 0.f, 0.f};

  // ---- layer 1 K-loop (KT=12): A depth-1, B depth-2 register pipeline ----
  {
    const u16* aw = w1b + (size_t)(w * 64 + l15) * 32 + quad * 8;
    const u16* bx = xin + (size_t)panel * 24576 + (size_t)l15 * 32 + quad * 8;
    short8 af[2][4], bf[3][4];
#pragma unroll
    for (int m = 0; m < 4; ++m)
      af[0][m] = *(const short8*)(aw + m * 512);
#pragma unroll
    for (int n = 0; n < 4; ++n)
      bf[0][n] = *(const short8*)(bx + n * 512);
#pragma unroll
    for (int n = 0; n < 4; ++n)
      bf[1][n] = *(const short8*)(bx + 2048 + n * 512);
#pragma unroll
    for (int kt = 0; kt < 12; ++kt) {
      int cur = kt & 1, nxt = cur ^ 1;
      if (kt < 11) {
#pragma unroll
        for (int m = 0; m < 4; ++m)
          af[nxt][m] = *(const short8*)(aw + (kt + 1) * 8192 + m * 512);
      }
      if (kt < 10) {
#pragma unroll
        for (int n = 0; n < 4; ++n)
          bf[(kt + 2) % 3][n] = *(const short8*)(bx + (kt + 2) * 2048 + n * 512);
      }
#pragma unroll
      for (int m = 0; m < 4; ++m)
#pragma unroll
        for (int n = 0; n < 4; ++n)
          acc[m][n] = __builtin_amdgcn_mfma_f32_16x16x32_bf16(af[cur][m], bf[kt % 3][n], acc[m][n], 0, 0, 0);
    }
  }

  // ---- epilogue 1: BN+ReLU -> bf16 -> LDS y1 tile (blocked, stride 40) ----
  {
    float al[4][4], bt[4][4];
#pragma unroll
    for (int m = 0; m < 4; ++m)
#pragma unroll
      for (int r = 0; r < 4; ++r) {
        int o = w * 64 + m * 16 + quad * 4 + r;
        al[m][r] = al1[o];
        bt[m][r] = bt1[o];
      }
#pragma unroll
    for (int m = 0; m < 4; ++m) {
      int kt2 = w * 2 + (m >> 1);
      int osub = (m & 1) * 16 + quad * 4;
#pragma unroll
      for (int n = 0; n < 4; ++n) {
        int col = n * 16 + l15;
        ushort4 pk;
        pk.x = f2b(fmaxf(fmaf(al[m][0], acc[m][n][0], bt[m][0]), 0.f));
        pk.y = f2b(fmaxf(fmaf(al[m][1], acc[m][n][1], bt[m][1]), 0.f));
        pk.z = f2b(fmaxf(fmaf(al[m][2], acc[m][n][2], bt[m][2]), 0.f));
        pk.w = f2b(fmaxf(fmaf(al[m][3], acc[m][n][3], bt[m][3]), 0.f));
        *(ushort4*)&y1t[(kt2 * 64 + col) * 40 + osub] = pk;
      }
    }
  }
  __syncthreads();

  // ---- layer 2 K-loop (KT=8): A global (depth-1 pipeline), B from LDS ----
#pragma unroll
  for (int m = 0; m < 4; ++m)
#pragma unroll
    for (int n = 0; n < 4; ++n)
      acc[m][n] = (f32x4){0.f, 0.f, 0.f, 0.f};
  {
    const u16* aw = w2b + (size_t)(w * 64 + l15) * 32 + quad * 8;
    short8 af[2][4];
#pragma unroll
    for (int m = 0; m < 4; ++m)
      af[0][m] = *(const short8*)(aw + m * 512);
#pragma unroll
    for (int kt = 0; kt < 8; ++kt) {
      int cur = kt & 1, nxt = cur ^ 1;
      if (kt < 7) {
#pragma unroll
        for (int m = 0; m < 4; ++m)
          af[nxt][m] = *(const short8*)(aw + (kt + 1) * 8192 + m * 512);
      }
      short8 bf[4];
#pragma unroll
      for (int n = 0; n < 4; ++n)
        bf[n] = *(const short8*)&y1t[(kt * 64 + n * 16 + l15) * 40 + quad * 8];
#pragma unroll
      for (int m = 0; m < 4; ++m)
#pragma unroll
        for (int n = 0; n < 4; ++n)
          acc[m][n] = __builtin_amdgcn_mfma_f32_16x16x32_bf16(af[cur][m], bf[n], acc[m][n], 0, 0, 0);
    }
  }

  // ---- epilogue 2: BN+ReLU -> f32 out [b][256][8192] ----
  {
    float al[4][4], bt[4][4];
#pragma unroll
    for (int m = 0; m < 4; ++m)
#pragma unroll
      for (int r = 0; r < 4; ++r) {
        int o = w * 64 + m * 16 + quad * 4 + r;
        al[m][r] = al2[o];
        bt[m][r] = bt2[o];
      }
    int bb = panel >> 7;
    int n1base = (panel & 127) * 64;
#pragma unroll
    for (int m = 0; m < 4; ++m)
#pragma unroll
      for (int n = 0; n < 4; ++n) {
        int col = n * 16 + l15;
#pragma unroll
        for (int r = 0; r < 4; ++r) {
          int o = w * 64 + m * 16 + quad * 4 + r;
          float vv = fmaxf(fmaf(al[m][r], acc[m][n][r], bt[m][r]), 0.f);
          fout[(size_t)(bb * 256 + o) * 8192 + n1base + col] = vv;
        }
      }
  }
}

// ---------------------------------------------------------------------------
// ws layout (bytes):
//   [0,          50331648)  xb   bf16 [1024 panels][12][64][32]   48 MB
//   [50331648,   58720256)  f2t  bf16 [8][2048][256]               8 MB
//   [83886080,   84082688)  w1b  bf16 blocked
//   [84082688,   84213760)  w2b  bf16 blocked
//   [84213760,   84217856)  al1/bt1/al2/bt2 f32
// ---------------------------------------------------------------------------
extern "C" void kernel_launch(void* const* d_in, const int* in_sizes, int n_in,
                              void* d_out, int out_size, void* d_ws, size_t ws_size,
                              hipStream_t stream) {
  const float* xyz1 = (const float*)d_in[0];
  const float* xyz2 = (const float*)d_in[1];
  const float* f1   = (const float*)d_in[2];
  const float* f2   = (const float*)d_in[3];
  const float* w1   = (const float*)d_in[4];
  const float* b1   = (const float*)d_in[5];
  const float* g1   = (const float*)d_in[6];
  const float* be1  = (const float*)d_in[7];
  const float* m1   = (const float*)d_in[8];
  const float* v1   = (const float*)d_in[9];
  const float* w2   = (const float*)d_in[10];
  const float* b2   = (const float*)d_in[11];
  const float* g2   = (const float*)d_in[12];
  const float* be2  = (const float*)d_in[13];
  const float* m2   = (const float*)d_in[14];
  const float* v2   = (const float*)d_in[15];

  char* ws = (char*)d_ws;
  u16* xb   = (u16*)(ws);
  u16* f2t  = (u16*)(ws + 50331648);
  u16* w1b  = (u16*)(ws + 83886080);
  u16* w2b  = (u16*)(ws + 84082688);
  float* al1 = (float*)(ws + 84213760);
  float* bt1 = (float*)(ws + 84214784);
  float* al2 = (float*)(ws + 84215808);
  float* bt2 = (float*)(ws + 84216832);
  float* out = (float*)d_out;

  prep_transpose_kernel<<<4738, 256, 0, stream>>>(
      f2, f2t, w1, b1, g1, be1, m1, v1, w2, b2, g2, be2, m2, v2,
      w1b, w2b, al1, bt1, al2, bt2);
  knn_interp_kernel<<<1024, 256, 0, stream>>>(xyz1, xyz2, f1, f2t, xb);
  gemm_fused_kernel<<<1024, 256, 0, stream>>>(xb, w1b, w2b, al1, bt1, al2, bt2, out);
}

// Round 13
// 211.926 us; speedup vs baseline: 1.4915x; 1.0147x over previous
//
#include <hip/hip_runtime.h>
#include <hip/hip_bf16.h>

typedef unsigned short u16;
typedef __attribute__((ext_vector_type(4))) float f32x4;
typedef __attribute__((ext_vector_type(8))) short short8;
typedef __attribute__((address_space(1))) const unsigned int as1_u32;
typedef __attribute__((address_space(3))) unsigned int as3_u32;

#define BN_EPS 1e-5f

__device__ __forceinline__ u16 f2b(float x) {
  union { float f; unsigned int u; } v; v.f = x;
  unsigned int r = (v.u + 0x7FFFu + ((v.u >> 16) & 1u)) >> 16;
  return (u16)r;
}
__device__ __forceinline__ float b2f(u16 u) {
  union { unsigned int u; float f; } v; v.u = ((unsigned int)u) << 16;
  return v.f;
}
__device__ __forceinline__ float asf(unsigned u) {
  union { unsigned u; float f; } v; v.u = u; return v.f;
}

// ---------------------------------------------------------------------------
// prep + transpose fused (round-2/5 proven version).
// ---------------------------------------------------------------------------
__global__ void prep_transpose_kernel(
    const float* __restrict__ f2, u16* __restrict__ f2t,
    const float* __restrict__ w1, const float* __restrict__ b1,
    const float* __restrict__ g1, const float* __restrict__ be1,
    const float* __restrict__ m1, const float* __restrict__ v1,
    const float* __restrict__ w2, const float* __restrict__ b2,
    const float* __restrict__ g2, const float* __restrict__ be2,
    const float* __restrict__ m2, const float* __restrict__ v2,
    u16* __restrict__ w1b, u16* __restrict__ w2b,
    float* __restrict__ al1, float* __restrict__ bt1,
    float* __restrict__ al2, float* __restrict__ bt2) {
  __shared__ float tile[32][33];
  int t = threadIdx.x;
  int blk = blockIdx.x;
  if (blk < 4096) {
    int tx = t & 31, ty = t >> 5;        // ty in [0,8)
    int b = (blk >> 9) & 7;
    int n2t = (blk & 63) * 32, ct = ((blk >> 6) & 7) * 32;
#pragma unroll
    for (int i = 0; i < 4; ++i) {
      int c = ct + ty + i * 8;
      tile[ty + i * 8][tx] = f2[((size_t)b * 256 + c) * 2048 + n2t + tx];
    }
    __syncthreads();
#pragma unroll
    for (int i = 0; i < 4; ++i) {
      int n2 = n2t + ty + i * 8;
      f2t[((size_t)b * 2048 + n2) * 256 + ct + tx] = f2b(tile[tx][ty + i * 8]);
    }
  } else if (blk < 4480) {               // w1: 256x384
    int id = (blk - 4096) * 256 + t;
    unsigned o = (unsigned)id / 384u;
    unsigned c = (unsigned)id % 384u;
    w1b[(c >> 5) * 8192 + o * 32 + (c & 31)] = f2b(w1[id]);
  } else if (blk < 4736) {               // w2: 256x256
    int j = (blk - 4480) * 256 + t;
    unsigned o = (unsigned)j >> 8;
    unsigned c = (unsigned)j & 255u;
    w2b[(c >> 5) * 8192 + o * 32 + (c & 31)] = f2b(w2[j]);
  } else if (blk == 4736) {
    float a = g1[t] / sqrtf(v1[t] + BN_EPS);
    al1[t] = a;
    bt1[t] = (b1[t] - m1[t]) * a + be1[t];
  } else {
    float a = g2[t] / sqrtf(v2[t] + BN_EPS);
    al2[t] = a;
    bt2[t] = (b2[t] - m2[t]) * a + be2[t];
  }
}

// ---------------------------------------------------------------------------
// knn + interp + skip-copy — R11 VERBATIM (best measured: 68.7 us).
// Exact comparator (cmps + gated med3/min network) — R12 proved any
// comparator quantization changes selection; selection must be exact.
// ---------------------------------------------------------------------------
__global__ __launch_bounds__(256) void knn_interp_kernel(
    const float* __restrict__ xyz1, const float* __restrict__ xyz2,
    const float* __restrict__ f1, const u16* __restrict__ f2t,
    u16* __restrict__ xb) {
  union Lds {
    struct { float4 pts[2048]; float md[256 * 3]; u16 mi[256 * 3]; } a;
    float f1t[128 * 65];
  };
  __shared__ Lds lds;
  __shared__ float wts[64 * 3];
  __shared__ int idxs[64 * 3];           // premultiplied by 256

  int t = threadIdx.x;
  int b = blockIdx.x >> 7;
  int n1_0 = (blockIdx.x & 127) * 64;
  int panel = blockIdx.x;                // = b*128 + tile

  // phase 0: stage candidates (x,y,z,|x|^2)
  const float* x2 = xyz2 + b * 3 * 2048;
  for (int j = t; j < 2048; j += 256) {
    float cx = x2[j], cy = x2[2048 + j], cz = x2[4096 + j];
    float nsq = (cx * cx + cy * cy) + cz * cz;
    lds.a.pts[j] = make_float4(cx, cy, cz, nsq);
  }
  __syncthreads();

  const float* x1 = xyz1 + b * 3 * 8192;

  // phase 1: sliced top-3; lane = query, wave = slice (broadcast LDS reads)
  {
    int p = t & 63, s = t >> 6;
    int n1 = n1_0 + p;
    float bx = x1[n1], by = x1[8192 + n1], bz = x1[16384 + n1];
    float nx = -2.f * bx, ny = -2.f * by, nz = -2.f * bz;
    // comparator value: sq' = |c|^2 - 2 q.c  (biased by -|q|^2, rank-equal)
    float d0 = 3.4e38f, d1 = 3.4e38f, d2 = 3.4e38f;
    int i0 = 0, i1 = 0, i2 = 0;
    int jb = s * 512;

#define KNN_UPD(cv, jv)                                                      \
    {                                                                        \
      float sq = fmaf(nx, (cv).x, fmaf(ny, (cv).y, fmaf(nz, (cv).z, (cv).w))); \
      if (__any(sq < d2)) {                                                  \
        bool c0 = sq < d0, c1 = sq < d1, c2 = sq < d2;                       \
        i2 = c1 ? i1 : (c2 ? (jv) : i2);                                     \
        i1 = c0 ? i0 : (c1 ? (jv) : i1);                                     \
        i0 = c0 ? (jv) : i0;                                                 \
        d2 = __builtin_amdgcn_fmed3f(sq, d1, d2);                            \
        d1 = __builtin_amdgcn_fmed3f(sq, d0, d1);                            \
        d0 = fminf(sq, d0);                                                  \
      }                                                                      \
    }

    for (int jj = 0; jj < 512; jj += 8) {
      float4 c0v = lds.a.pts[jb + jj + 0];
      float4 c1v = lds.a.pts[jb + jj + 1];
      float4 c2v = lds.a.pts[jb + jj + 2];
      float4 c3v = lds.a.pts[jb + jj + 3];
      float4 c4v = lds.a.pts[jb + jj + 4];
      float4 c5v = lds.a.pts[jb + jj + 5];
      float4 c6v = lds.a.pts[jb + jj + 6];
      float4 c7v = lds.a.pts[jb + jj + 7];
      KNN_UPD(c0v, jb + jj + 0);
      KNN_UPD(c1v, jb + jj + 1);
      KNN_UPD(c2v, jb + jj + 2);
      KNN_UPD(c3v, jb + jj + 3);
      KNN_UPD(c4v, jb + jj + 4);
      KNN_UPD(c5v, jb + jj + 5);
      KNN_UPD(c6v, jb + jj + 6);
      KNN_UPD(c7v, jb + jj + 7);
    }
#undef KNN_UPD
    lds.a.md[t * 3 + 0] = d0; lds.a.md[t * 3 + 1] = d1; lds.a.md[t * 3 + 2] = d2;
    lds.a.mi[t * 3 + 0] = (u16)i0; lds.a.mi[t * 3 + 1] = (u16)i1; lds.a.mi[t * 3 + 2] = (u16)i2;
  }
  __syncthreads();
  if (t < 64) {
    // merge slices s=0..3 in ascending-index order (preserves tie-break)
    float d0 = 3.4e38f, d1 = 3.4e38f, d2 = 3.4e38f;
    int i0 = 0, i1 = 0, i2 = 0;
#pragma unroll
    for (int s = 0; s < 4; ++s) {
#pragma unroll
      for (int k = 0; k < 3; ++k) {
        float d = lds.a.md[(s * 64 + t) * 3 + k];
        int i = (int)lds.a.mi[(s * 64 + t) * 3 + k];
        bool c0 = d < d0, c1 = d < d1, c2 = d < d2;
        i2 = c1 ? i1 : (c2 ? i : i2);
        i1 = c0 ? i0 : (c1 ? i : i1);
        i0 = c0 ? i : i0;
        d2 = c1 ? d1 : (c2 ? d : d2);
        d1 = c0 ? d0 : (c1 ? d : d1);
        d0 = c0 ? d : d0;
      }
    }
    // un-bias: recompute |q|^2 for this query (3 L1-hot loads, 64 threads)
    int n1 = n1_0 + t;
    float bx = x1[n1], by = x1[8192 + n1], bz = x1[16384 + n1];
    float nn = (bx * bx + by * by) + bz * bz;
    float e0 = fmaxf(d0 + nn, 1e-10f), e1 = fmaxf(d1 + nn, 1e-10f), e2 = fmaxf(d2 + nn, 1e-10f);
    float w0 = 1.0f / e0, w1 = 1.0f / e1, w2 = 1.0f / e2;
    float sm = (w0 + w1) + w2;
    wts[t * 3 + 0] = w0 / sm; wts[t * 3 + 1] = w1 / sm; wts[t * 3 + 2] = w2 / sm;
    idxs[t * 3 + 0] = i0 * 256; idxs[t * 3 + 1] = i1 * 256; idxs[t * 3 + 2] = i2 * 256;
  }
  __syncthreads();

  // phase 2: interp 256 channels as 64 channel-quads x 4 query groups
  {
    const u16* f2tb = f2t + (size_t)b * 2048 * 256;
    int tc = t & 63;                     // channel quad: channels 4tc..4tc+3
    int qg = t >> 6;                     // query group (uniform per wave)
    int ce = (4 * tc) & 31;              // channel offset within 32-block
    size_t xbase = (size_t)panel * 24576 + (size_t)(tc >> 3) * 2048 + ce;
#pragma unroll 4
    for (int p2 = 0; p2 < 16; ++p2) {
      int p = p2 * 4 + qg;
      int j0 = idxs[p * 3 + 0], j1 = idxs[p * 3 + 1], j2 = idxs[p * 3 + 2];
      float w0 = wts[p * 3 + 0], w1 = wts[p * 3 + 1], w2 = wts[p * 3 + 2];
      uint2 a0 = *(const uint2*)&f2tb[j0 + 4 * tc];
      uint2 a1 = *(const uint2*)&f2tb[j1 + 4 * tc];
      uint2 a2 = *(const uint2*)&f2tb[j2 + 4 * tc];
      float v0 = (w0 * asf(a0.x << 16) + w1 * asf(a1.x << 16)) + w2 * asf(a2.x << 16);
      float v1 = (w0 * asf(a0.x & 0xffff0000u) + w1 * asf(a1.x & 0xffff0000u))
                 + w2 * asf(a2.x & 0xffff0000u);
      float v2 = (w0 * asf(a0.y << 16) + w1 * asf(a1.y << 16)) + w2 * asf(a2.y << 16);
      float v3 = (w0 * asf(a0.y & 0xffff0000u) + w1 * asf(a1.y & 0xffff0000u))
                 + w2 * asf(a2.y & 0xffff0000u);
      uint2 pk;
      pk.x = (unsigned)f2b(v0) | ((unsigned)f2b(v1) << 16);
      pk.y = (unsigned)f2b(v2) | ((unsigned)f2b(v3) << 16);
      *(uint2*)&xb[xbase + (size_t)p * 32] = pk;
    }
  }
  __syncthreads();   // before aliasing lds.a with lds.f1t

  // phase 3: skip features (channels 256..383) via LDS transpose
  {
    const float* f1b = f1 + (size_t)b * 128 * 8192 + n1_0;
    for (int it = 0; it < 32; ++it) {
      int c = it * 4 + (t >> 6);
      int n = t & 63;
      lds.f1t[c * 65 + n] = f1b[(size_t)c * 8192 + n];
    }
    __syncthreads();
    for (int it = 0; it < 32; ++it) {
      int v = it * 256 + t;
      int c = v & 127, p = v >> 7;
      float val = lds.f1t[c * 65 + p];
      xb[(size_t)panel * 24576 + (size_t)(8 + (c >> 5)) * 2048 + p * 32 + (c & 31)] = f2b(val);
    }
  }
}

// ---------------------------------------------------------------------------
// FUSED 2-layer GEMM. NEW: layer-1 B kt 0..7 (32 KB) DMA-staged into LDS via
// global_load_lds width-16 (linear dest = exact xb panel layout; wave-uniform
// base + lane*16) and shared by all 4 waves — removes the 4x redundant
// global B fetch and all mid-loop vmcnt deps for 8 of 12 kt. kt 8..11 keep
// the proven bf[3] depth-2 global pipeline. The y1 tile ALIASES the staging
// buffer (union, barrier-separated: B fully consumed before epilogue 1).
// LDS = 40960 B (unchanged) -> 4 blocks/CU preserved.
// ---------------------------------------------------------------------------
__global__ __launch_bounds__(256) void gemm_fused_kernel(
    const u16* __restrict__ xin, const u16* __restrict__ w1b,
    const u16* __restrict__ w2b,
    const float* __restrict__ al1, const float* __restrict__ bt1,
    const float* __restrict__ al2, const float* __restrict__ bt2,
    float* __restrict__ fout) {
  union LdsU {
    u16 bstage[8 * 2048];                // 32768 B: xb panel kt 0..7, linear
    u16 y1t[8 * 64 * 40];                // 40960 B
  };
  __shared__ LdsU u;
  int t = threadIdx.x;
  int panel = blockIdx.x;
  int w = t >> 6, lane = t & 63, l15 = lane & 15, quad = lane >> 4;

  // ---- async DMA: stage xb[panel] kt 0..7 into LDS (8 x 4096 B chunks) ----
  {
    const u16* src = xin + (size_t)panel * 24576;
#pragma unroll
    for (int i = 0; i < 8; ++i) {
      int off = i * 2048 + w * 512 + lane * 8;   // u16 elements
      __builtin_amdgcn_global_load_lds(
          (as1_u32*)(src + off),
          (as3_u32*)&u.bstage[i * 2048 + w * 512], 16, 0, 0);
    }
  }

  f32x4 acc[4][4];
#pragma unroll
  for (int m = 0; m < 4; ++m)
#pragma unroll
    for (int n = 0; n < 4; ++n)
      acc[m][n] = (f32x4){0.f, 0.f, 0.f, 0.f};

  // ---- layer 1 K-loop (KT=12): B kt<8 from LDS, kt>=8 depth-2 global ----
  {
    const u16* aw = w1b + (size_t)(w * 64 + l15) * 32 + quad * 8;
    const u16* bxg = xin + (size_t)panel * 24576 + (size_t)l15 * 32 + quad * 8;
    short8 af[2][4], bf[3][4];
#pragma unroll
    for (int m = 0; m < 4; ++m)
      af[0][m] = *(const short8*)(aw + m * 512);
    __syncthreads();                     // staging complete (vmcnt drained)
#pragma unroll
    for (int kt = 0; kt < 12; ++kt) {
      int cur = kt & 1, nxt = cur ^ 1;
      if (kt < 11) {
#pragma unroll
        for (int m = 0; m < 4; ++m)
          af[nxt][m] = *(const short8*)(aw + (kt + 1) * 8192 + m * 512);
      }
      if (kt >= 6 && kt < 10) {
#pragma unroll
        for (int n = 0; n < 4; ++n)
          bf[(kt + 2) % 3][n] = *(const short8*)(bxg + (kt + 2) * 2048 + n * 512);
      }
      short8 bcur[4];
      if (kt < 8) {
#pragma unroll
        for (int n = 0; n < 4; ++n)
          bcur[n] = *(const short8*)&u.bstage[kt * 2048 + (n * 16 + l15) * 32 + quad * 8];
      } else {
#pragma unroll
        for (int n = 0; n < 4; ++n)
          bcur[n] = bf[kt % 3][n];
      }
#pragma unroll
      for (int m = 0; m < 4; ++m)
#pragma unroll
        for (int n = 0; n < 4; ++n)
          acc[m][n] = __builtin_amdgcn_mfma_f32_16x16x32_bf16(af[cur][m], bcur[n], acc[m][n], 0, 0, 0);
    }
  }
  __syncthreads();                       // all bstage reads done before alias

  // ---- epilogue 1: BN+ReLU -> bf16 -> y1t (blocked, stride 40) ----
  {
    float al[4][4], bt[4][4];
#pragma unroll
    for (int m = 0; m < 4; ++m)
#pragma unroll
      for (int r = 0; r < 4; ++r) {
        int o = w * 64 + m * 16 + quad * 4 + r;
        al[m][r] = al1[o];
        bt[m][r] = bt1[o];
      }
#pragma unroll
    for (int m = 0; m < 4; ++m) {
      int kt2 = w * 2 + (m >> 1);
      int osub = (m & 1) * 16 + quad * 4;
#pragma unroll
      for (int n = 0; n < 4; ++n) {
        int col = n * 16 + l15;
        ushort4 pk;
        pk.x = f2b(fmaxf(fmaf(al[m][0], acc[m][n][0], bt[m][0]), 0.f));
        pk.y = f2b(fmaxf(fmaf(al[m][1], acc[m][n][1], bt[m][1]), 0.f));
        pk.z = f2b(fmaxf(fmaf(al[m][2], acc[m][n][2], bt[m][2]), 0.f));
        pk.w = f2b(fmaxf(fmaf(al[m][3], acc[m][n][3], bt[m][3]), 0.f));
        *(ushort4*)&u.y1t[(kt2 * 64 + col) * 40 + osub] = pk;
      }
    }
  }
  __syncthreads();

  // ---- layer 2 K-loop (KT=8): A global (depth-1 pipeline), B from y1t ----
#pragma unroll
  for (int m = 0; m < 4; ++m)
#pragma unroll
    for (int n = 0; n < 4; ++n)
      acc[m][n] = (f32x4){0.f, 0.f, 0.f, 0.f};
  {
    const u16* aw = w2b + (size_t)(w * 64 + l15) * 32 + quad * 8;
    short8 af[2][4];
#pragma unroll
    for (int m = 0; m < 4; ++m)
      af[0][m] = *(const short8*)(aw + m * 512);
#pragma unroll
    for (int kt = 0; kt < 8; ++kt) {
      int cur = kt & 1, nxt = cur ^ 1;
      if (kt < 7) {
#pragma unroll
        for (int m = 0; m < 4; ++m)
          af[nxt][m] = *(const short8*)(aw + (kt + 1) * 8192 + m * 512);
      }
      short8 bf2[4];
#pragma unroll
      for (int n = 0; n < 4; ++n)
        bf2[n] = *(const short8*)&u.y1t[(kt * 64 + n * 16 + l15) * 40 + quad * 8];
#pragma unroll
      for (int m = 0; m < 4; ++m)
#pragma unroll
        for (int n = 0; n < 4; ++n)
          acc[m][n] = __builtin_amdgcn_mfma_f32_16x16x32_bf16(af[cur][m], bf2[n], acc[m][n], 0, 0, 0);
    }
  }

  // ---- epilogue 2: BN+ReLU -> f32 out [b][256][8192] ----
  {
    float al[4][4], bt[4][4];
#pragma unroll
    for (int m = 0; m < 4; ++m)
#pragma unroll
      for (int r = 0; r < 4; ++r) {
        int o = w * 64 + m * 16 + quad * 4 + r;
        al[m][r] = al2[o];
        bt[m][r] = bt2[o];
      }
    int bb = panel >> 7;
    int n1base = (panel & 127) * 64;
#pragma unroll
    for (int m = 0; m < 4; ++m)
#pragma unroll
      for (int n = 0; n < 4; ++n) {
        int col = n * 16 + l15;
#pragma unroll
        for (int r = 0; r < 4; ++r) {
          int o = w * 64 + m * 16 + quad * 4 + r;
          float vv = fmaxf(fmaf(al[m][r], acc[m][n][r], bt[m][r]), 0.f);
          fout[(size_t)(bb * 256 + o) * 8192 + n1base + col] = vv;
        }
      }
  }
}

// ---------------------------------------------------------------------------
// ws layout (bytes):
//   [0,          50331648)  xb   bf16 [1024 panels][12][64][32]   48 MB
//   [50331648,   58720256)  f2t  bf16 [8][2048][256]               8 MB
//   [83886080,   84082688)  w1b  bf16 blocked
//   [84082688,   84213760)  w2b  bf16 blocked
//   [84213760,   84217856)  al1/bt1/al2/bt2 f32
// ---------------------------------------------------------------------------
extern "C" void kernel_launch(void* const* d_in, const int* in_sizes, int n_in,
                              void* d_out, int out_size, void* d_ws, size_t ws_size,
                              hipStream_t stream) {
  const float* xyz1 = (const float*)d_in[0];
  const float* xyz2 = (const float*)d_in[1];
  const float* f1   = (const float*)d_in[2];
  const float* f2   = (const float*)d_in[3];
  const float* w1   = (const float*)d_in[4];
  const float* b1   = (const float*)d_in[5];
  const float* g1   = (const float*)d_in[6];
  const float* be1  = (const float*)d_in[7];
  const float* m1   = (const float*)d_in[8];
  const float* v1   = (const float*)d_in[9];
  const float* w2   = (const float*)d_in[10];
  const float* b2   = (const float*)d_in[11];
  const float* g2   = (const float*)d_in[12];
  const float* be2  = (const float*)d_in[13];
  const float* m2   = (const float*)d_in[14];
  const float* v2   = (const float*)d_in[15];

  char* ws = (char*)d_ws;
  u16* xb   = (u16*)(ws);
  u16* f2t  = (u16*)(ws + 50331648);
  u16* w1b  = (u16*)(ws + 83886080);
  u16* w2b  = (u16*)(ws + 84082688);
  float* al1 = (float*)(ws + 84213760);
  float* bt1 = (float*)(ws + 84214784);
  float* al2 = (float*)(ws + 84215808);
  float* bt2 = (float*)(ws + 84216832);
  float* out = (float*)d_out;

  prep_transpose_kernel<<<4738, 256, 0, stream>>>(
      f2, f2t, w1, b1, g1, be1, m1, v1, w2, b2, g2, be2, m2, v2,
      w1b, w2b, al1, bt1, al2, bt2);
  knn_interp_kernel<<<1024, 256, 0, stream>>>(xyz1, xyz2, f1, f2t, xb);
  gemm_fused_kernel<<<1024, 256, 0, stream>>>(xb, w1b, w2b, al1, bt1, al2, bt2, out);
}